// Round 4
// baseline (612.898 us; speedup 1.0000x reference)
//
#include <hip/hip_runtime.h>
#include <math.h>

#define N_NODES 50000
#define N_EDGES 800000
#define N_GRAPHS 512
#define M_PAD 50048   // N_NODES rounded up to 128

typedef unsigned short u16;
typedef unsigned int u32;
using bf16x8 = __attribute__((ext_vector_type(8))) short;
using floatx4 = __attribute__((ext_vector_type(4))) float;

__device__ __forceinline__ float bf2f(u16 h) {
    union { u32 u; float f; } v; v.u = ((u32)h) << 16; return v.f;
}
__device__ __forceinline__ u16 f2bf(float f) {
    union { float f; u32 u; } v; v.f = f;
    u32 u = v.u;
    return (u16)((u + 0x7FFFu + ((u >> 16) & 1u)) >> 16);
}

// ---------------------------------------------------------------------------
// CSR build
// ---------------------------------------------------------------------------
__global__ void count_int_kernel(const int* __restrict__ idx, int* __restrict__ cnt, int n) {
    int i = blockIdx.x * blockDim.x + threadIdx.x;
    if (i < n) atomicAdd(&cnt[idx[i]], 1);
}

__global__ void scan1_kernel(const int* __restrict__ degi, int* __restrict__ starts,
                             int* __restrict__ bsum) {
    __shared__ int s[256];
    int t = threadIdx.x, i = blockIdx.x * 256 + t;
    int v = (i < N_NODES) ? degi[i] : 0;
    s[t] = v; __syncthreads();
    for (int off = 1; off < 256; off <<= 1) {
        int x = (t >= off) ? s[t - off] : 0;
        __syncthreads();
        s[t] += x;
        __syncthreads();
    }
    if (i < N_NODES) starts[i] = s[t] - v;
    if (t == 255) bsum[blockIdx.x] = s[255];
}

__global__ void scan2_kernel(const int* __restrict__ bsum, int* __restrict__ boff,
                             int* __restrict__ starts, int nb) {
    __shared__ int s[256];
    int t = threadIdx.x;
    int v = (t < nb) ? bsum[t] : 0;
    s[t] = v; __syncthreads();
    for (int off = 1; off < 256; off <<= 1) {
        int x = (t >= off) ? s[t - off] : 0;
        __syncthreads();
        s[t] += x;
        __syncthreads();
    }
    if (t < nb) boff[t] = s[t] - v;
    if (t == nb - 1) starts[N_NODES] = s[t];
}

__global__ void scan3_kernel(int* __restrict__ starts, const int* __restrict__ boff) {
    int i = blockIdx.x * 256 + threadIdx.x;
    if (i < N_NODES) starts[i] += boff[blockIdx.x];
}

__global__ void fill_csr_kernel(const int* __restrict__ src, const int* __restrict__ dst,
                                const int* __restrict__ starts, int* __restrict__ cursor,
                                int* __restrict__ csr) {
    int e = blockIdx.x * blockDim.x + threadIdx.x;
    if (e >= N_EDGES) return;
    int d = dst[e];
    int p = atomicAdd(&cursor[d], 1);
    csr[starts[d] + p] = src[e];
}

__global__ void gstart_kernel(const int* __restrict__ batch, int* __restrict__ gstart) {
    int i = blockIdx.x * blockDim.x + threadIdx.x;
    if (i >= N_NODES) return;
    int b = batch[i];
    int bp = (i == 0) ? -1 : batch[i - 1];
    for (int g = bp + 1; g <= b; ++g) gstart[g] = i;
    if (i == N_NODES - 1)
        for (int g = b + 1; g <= N_GRAPHS; ++g) gstart[g] = N_NODES;
}

__global__ void cntinv_kernel(const int* __restrict__ gstart, float* __restrict__ cntinv) {
    int g = blockIdx.x * blockDim.x + threadIdx.x;
    if (g < N_GRAPHS) cntinv[g] = 1.0f / fmaxf((float)(gstart[g + 1] - gstart[g]), 1.0f);
}

// ---------------------------------------------------------------------------
// conversions
// ---------------------------------------------------------------------------
__global__ void conv_x_kernel(const float* __restrict__ x, u16* __restrict__ abuf1) {
    int i = blockIdx.x * blockDim.x + threadIdx.x;
    if (i >= N_NODES * 64) return;
    int n = i >> 6, c = i & 63;
    float v = (c < 50) ? x[n * 50 + c] : 0.0f;
    abuf1[(size_t)n * 128 + 64 + c] = f2bf(v);
}

template<int DIN, int DINP, int DOUT>
__global__ void conv_w_kernel(const float* __restrict__ Wl, const float* __restrict__ Wr,
                              u16* __restrict__ wbuf) {
    int i = blockIdx.x * blockDim.x + threadIdx.x;
    if (i >= DOUT * DINP) return;
    int o = i / DINP, c = i % DINP;
    float vl = (c < DIN) ? Wl[o * DIN + c] : 0.0f;
    float vr = (c < DIN) ? Wr[o * DIN + c] : 0.0f;
    wbuf[(size_t)o * 2 * DINP + c] = f2bf(vl);
    wbuf[(size_t)o * 2 * DINP + DINP + c] = f2bf(vr);
}

// ---------------------------------------------------------------------------
// CSR gather mean-aggregation, one wave per node, unroll-8 edge prefetch
// ---------------------------------------------------------------------------
template<int DINP>
__global__ __launch_bounds__(256) void csr_agg_kernel(const int* __restrict__ starts,
                                                      const int* __restrict__ csr,
                                                      u16* __restrict__ abuf) {
    constexpr int STRIDE = 2 * DINP;
    constexpr int C = (DINP >= 256) ? 4 : (DINP >= 128 ? 2 : 1);
    int wave = threadIdx.x >> 6, lane = threadIdx.x & 63;
    int n = blockIdx.x * 4 + wave;
    if (n >= N_NODES) return;
    int s0 = starts[n], s1 = starts[n + 1];
    float acc[C];
    #pragma unroll
    for (int c = 0; c < C; ++c) acc[c] = 0.0f;
    const u16* xin = abuf + DINP;

    auto accum = [&](int sidx) {
        const u16* p = xin + (size_t)sidx * STRIDE + lane * C;
        if constexpr (C == 1) {
            acc[0] += bf2f(p[0]);
        } else if constexpr (C == 2) {
            ushort2 u = *(const ushort2*)p;
            acc[0] += bf2f(u.x); acc[1] += bf2f(u.y);
        } else {
            ushort4 u = *(const ushort4*)p;
            acc[0] += bf2f(u.x); acc[1] += bf2f(u.y);
            acc[2] += bf2f(u.z); acc[3] += bf2f(u.w);
        }
    };

    int e = s0;
    for (; e + 8 <= s1; e += 8) {
        int i0 = csr[e],     i1 = csr[e + 1], i2 = csr[e + 2], i3 = csr[e + 3];
        int i4 = csr[e + 4], i5 = csr[e + 5], i6 = csr[e + 6], i7 = csr[e + 7];
        accum(i0); accum(i1); accum(i2); accum(i3);
        accum(i4); accum(i5); accum(i6); accum(i7);
    }
    for (; e < s1; ++e) accum(csr[e]);

    float sc = 1.0f / fmaxf((float)(s1 - s0), 1.0f);
    u16* o = abuf + (size_t)n * STRIDE + lane * C;
    #pragma unroll
    for (int c = 0; c < C; ++c) o[c] = f2bf(acc[c] * sc);
}

// ---------------------------------------------------------------------------
// Barrier-free bf16 MFMA GEMM: no LDS. Each wave owns an independent 64x64
// output tile; A/B fragments loaded directly global->VGPR in MFMA layout
// (row = lane&15, k-offset = (lane>>4)*8 : 4-lane x 16B = 64B segments).
// Manual register ping-pong prefetches slab k+1 while MFMA runs on slab k;
// with no __syncthreads the compiler issues fine-grained s_waitcnt vmcnt(N).
// All 4 waves of a block share the same A m-tile (L1/L2 reuse).
// ACT 0: leaky_relu, 1: relu.  MODE 0: store bf16.  MODE 1: pool atomicAdd.
// ---------------------------------------------------------------------------
template<int K, int NTILES, int ACT, int MODE>
__global__ __launch_bounds__(256) void gemm_bf16_kernel(
    const u16* __restrict__ A, const u16* __restrict__ W,
    const float* __restrict__ bias,
    u16* __restrict__ out, int outStride, int outOff,
    float* __restrict__ pool, const int* __restrict__ batch, int N)
{
    const int wave = threadIdx.x >> 6, lane = threadIdx.x & 63;
    const int g = blockIdx.x * 4 + wave;
    const int nt = g % NTILES, mt = g / NTILES;
    const int m0 = mt * 64, n0 = nt * 64;
    const int lm = lane & 15, lq = lane >> 4;

    const u16* pa = A + (size_t)(m0 + lm) * K + lq * 8;
    const u16* pw = W + (size_t)(n0 + lm) * K + lq * 8;

    constexpr int NKB = K / 32;
    bf16x8 af[2][4], bf[2][4];

    // prologue: slab 0
    #pragma unroll
    for (int mi = 0; mi < 4; ++mi) af[0][mi] = *(const bf16x8*)(pa + (size_t)mi * 16 * K);
    #pragma unroll
    for (int ni = 0; ni < 4; ++ni) bf[0][ni] = *(const bf16x8*)(pw + (size_t)ni * 16 * K);

    floatx4 acc[4][4] = {};

    #pragma unroll
    for (int kb = 0; kb < NKB; ++kb) {
        const int cur = kb & 1, nxt = cur ^ 1;
        if (kb + 1 < NKB) {
            const int ko = (kb + 1) * 32;
            #pragma unroll
            for (int mi = 0; mi < 4; ++mi)
                af[nxt][mi] = *(const bf16x8*)(pa + (size_t)mi * 16 * K + ko);
            #pragma unroll
            for (int ni = 0; ni < 4; ++ni)
                bf[nxt][ni] = *(const bf16x8*)(pw + (size_t)ni * 16 * K + ko);
        }
        #pragma unroll
        for (int mi = 0; mi < 4; ++mi)
            #pragma unroll
            for (int ni = 0; ni < 4; ++ni)
                acc[mi][ni] = __builtin_amdgcn_mfma_f32_16x16x32_bf16(
                    af[cur][mi], bf[cur][ni], acc[mi][ni], 0, 0, 0);
    }

    // epilogue: D row=node (m0+mi*16+lq*4+r), col=o (n0+ni*16+lm)
    #pragma unroll
    for (int mi = 0; mi < 4; ++mi) {
        int node0 = m0 + mi * 16 + lq * 4;
        int b0 = -1, b3 = -2;
        if (MODE == 1) {
            b0 = (node0 < N) ? batch[node0] : -1;
            b3 = (node0 + 3 < N) ? batch[node0 + 3] : -2;
        }
        #pragma unroll
        for (int ni = 0; ni < 4; ++ni) {
            int o = n0 + ni * 16 + lm;
            float bi = bias[o];
            if (MODE == 0) {
                #pragma unroll
                for (int r = 0; r < 4; ++r) {
                    int node = node0 + r;
                    if (node >= N) continue;
                    float v = acc[mi][ni][r] + bi;
                    if (ACT == 0) v = (v > 0.0f) ? v : 0.01f * v;
                    else          v = fmaxf(v, 0.0f);
                    out[(size_t)node * outStride + outOff + o] = f2bf(v);
                }
            } else {
                float v[4];
                #pragma unroll
                for (int r = 0; r < 4; ++r)
                    v[r] = (node0 + r < N) ? fmaxf(acc[mi][ni][r] + bi, 0.0f) : 0.0f;
                if (b0 == b3) {
                    atomicAdd(&pool[(size_t)b0 * 512 + o], v[0] + v[1] + v[2] + v[3]);
                } else {
                    for (int r = 0; r < 4; ++r)
                        if (node0 + r < N)
                            atomicAdd(&pool[(size_t)batch[node0 + r] * 512 + o], v[r]);
                }
            }
        }
    }
}

// ---------------------------------------------------------------------------
// small dense layers over 512 graph rows (fp32 head)
// ---------------------------------------------------------------------------
template<int DIN, int DOUT, int ACT>
__global__ void dense_small_kernel(const float* __restrict__ X,
                                   const float* __restrict__ W,
                                   const float* __restrict__ b,
                                   const float* __restrict__ scale,
                                   float* __restrict__ Y)
{
    __shared__ float xs[DIN];
    const int g = blockIdx.x;
    const float sc = scale ? scale[g] : 1.0f;
    for (int k = threadIdx.x; k < DIN; k += blockDim.x)
        xs[k] = X[g * DIN + k] * sc;
    __syncthreads();
    for (int o = threadIdx.x; o < DOUT; o += blockDim.x) {
        float s = b[o];
        #pragma unroll 4
        for (int k = 0; k < DIN; ++k) s += xs[k] * W[o * DIN + k];
        if (ACT == 1) s = fmaxf(s, 0.0f);
        if (ACT == 2) s = 1.0f / (1.0f + expf(-s));
        Y[g * DOUT + o] = s;
    }
}

// ---------------------------------------------------------------------------
extern "C" void kernel_launch(void* const* d_in, const int* in_sizes, int n_in,
                              void* d_out, int out_size, void* d_ws, size_t ws_size,
                              hipStream_t stream)
{
    const float* x     = (const float*)d_in[0];
    const int*   ei    = (const int*)  d_in[1];
    const int*   batch = (const int*)  d_in[2];
    const float* Wl1   = (const float*)d_in[3];
    const float* bl1   = (const float*)d_in[4];
    const float* Wr1   = (const float*)d_in[5];
    const float* Wl2   = (const float*)d_in[6];
    const float* bl2   = (const float*)d_in[7];
    const float* Wr2   = (const float*)d_in[8];
    const float* Wl3   = (const float*)d_in[9];
    const float* bl3   = (const float*)d_in[10];
    const float* Wr3   = (const float*)d_in[11];
    const float* Wf1   = (const float*)d_in[12];
    const float* bf1   = (const float*)d_in[13];
    const float* Wf2   = (const float*)d_in[14];
    const float* bf2   = (const float*)d_in[15];
    const float* Wo    = (const float*)d_in[16];
    const float* bo    = (const float*)d_in[17];

    const int* src = ei;
    const int* dst = ei + N_EDGES;

    char* p = (char*)d_ws;
    auto alloc = [&](size_t bytes) { char* r = p; p += (bytes + 255) & ~(size_t)255; return r; };
    int*   degi   = (int*)  alloc(50176 * 4);
    int*   starts = (int*)  alloc(50432 * 4);
    int*   bsum   = (int*)  alloc(256 * 4);
    int*   boff   = (int*)  alloc(256 * 4);
    int*   cursor = (int*)  alloc(50176 * 4);
    int*   csr    = (int*)  alloc((size_t)N_EDGES * 4);
    int*   gstart = (int*)  alloc(513 * 4);
    float* cntinv = (float*)alloc(512 * 4);
    float* pool   = (float*)alloc((size_t)512 * 512 * 4);
    float* x4     = (float*)alloc((size_t)512 * 256 * 4);
    float* x5     = (float*)alloc((size_t)512 * 128 * 4);
    u16*   abuf1  = (u16*)  alloc((size_t)M_PAD * 128 * 2);
    u16*   abuf2  = (u16*)  alloc((size_t)M_PAD * 256 * 2);
    u16*   abuf3  = (u16*)  alloc((size_t)M_PAD * 512 * 2);
    u16*   wb1    = (u16*)  alloc((size_t)128 * 128 * 2);
    u16*   wb2    = (u16*)  alloc((size_t)256 * 256 * 2);
    u16*   wb3    = (u16*)  alloc((size_t)512 * 512 * 2);

    // ---- CSR build ----
    hipMemsetAsync(degi, 0, 50176 * 4, stream);
    hipMemsetAsync(cursor, 0, 50176 * 4, stream);
    count_int_kernel<<<(N_EDGES + 255) / 256, 256, 0, stream>>>(dst, degi, N_EDGES);
    scan1_kernel<<<196, 256, 0, stream>>>(degi, starts, bsum);
    scan2_kernel<<<1, 256, 0, stream>>>(bsum, boff, starts, 196);
    scan3_kernel<<<196, 256, 0, stream>>>(starts, boff);
    fill_csr_kernel<<<(N_EDGES + 255) / 256, 256, 0, stream>>>(src, dst, starts, cursor, csr);
    gstart_kernel<<<196, 256, 0, stream>>>(batch, gstart);
    cntinv_kernel<<<2, 256, 0, stream>>>(gstart, cntinv);

    // ---- conversions ----
    conv_x_kernel<<<(N_NODES * 64 + 255) / 256, 256, 0, stream>>>(x, abuf1);
    conv_w_kernel<50, 64, 128><<<(128 * 64 + 255) / 256, 256, 0, stream>>>(Wl1, Wr1, wb1);
    conv_w_kernel<128, 128, 256><<<(256 * 128 + 255) / 256, 256, 0, stream>>>(Wl2, Wr2, wb2);
    conv_w_kernel<256, 256, 512><<<(512 * 256 + 255) / 256, 256, 0, stream>>>(Wl3, Wr3, wb3);

    const int GB = 12500;
    const int MT = M_PAD / 64;   // 782 m-tiles of 64 rows

    // ---- layer 1: 50 -> 128, leaky_relu ----
    csr_agg_kernel<64><<<GB, 256, 0, stream>>>(starts, csr, abuf1);
    gemm_bf16_kernel<128, 2, 0, 0><<<MT * 2 / 4, 256, 0, stream>>>(
        abuf1, wb1, bl1, abuf2, 256, 128, nullptr, nullptr, N_NODES);

    // ---- layer 2: 128 -> 256, relu ----
    csr_agg_kernel<128><<<GB, 256, 0, stream>>>(starts, csr, abuf2);
    gemm_bf16_kernel<256, 4, 1, 0><<<MT * 4 / 4, 256, 0, stream>>>(
        abuf2, wb2, bl2, abuf3, 512, 256, nullptr, nullptr, N_NODES);

    // ---- layer 3: 256 -> 512, relu + fused pool sum ----
    csr_agg_kernel<256><<<GB, 256, 0, stream>>>(starts, csr, abuf3);
    hipMemsetAsync(pool, 0, (size_t)512 * 512 * 4, stream);
    gemm_bf16_kernel<512, 8, 1, 1><<<MT * 8 / 4, 256, 0, stream>>>(
        abuf3, wb3, bl3, nullptr, 0, 0, pool, batch, N_NODES);

    // ---- MLP head (fp32) ----
    dense_small_kernel<512, 256, 1><<<N_GRAPHS, 256, 0, stream>>>(pool, Wf1, bf1, cntinv, x4);
    dense_small_kernel<256, 128, 1><<<N_GRAPHS, 128, 0, stream>>>(x4, Wf2, bf2, nullptr, x5);
    dense_small_kernel<128, 1, 2><<<N_GRAPHS, 64, 0, stream>>>(x5, Wo, bo, nullptr, (float*)d_out);
}

// Round 5
// 520.619 us; speedup vs baseline: 1.1772x; 1.1772x over previous
//
#include <hip/hip_runtime.h>
#include <math.h>

#define N_NODES 50000
#define N_EDGES 800000
#define N_GRAPHS 512
#define M_PAD 50048   // N_NODES rounded up to 128

typedef unsigned short u16;
typedef unsigned int u32;
using bf16x8 = __attribute__((ext_vector_type(8))) short;
using floatx4 = __attribute__((ext_vector_type(4))) float;

__device__ __forceinline__ float bf2f(u16 h) {
    union { u32 u; float f; } v; v.u = ((u32)h) << 16; return v.f;
}
__device__ __forceinline__ u16 f2bf(float f) {
    union { float f; u32 u; } v; v.f = f;
    u32 u = v.u;
    return (u16)((u + 0x7FFFu + ((u >> 16) & 1u)) >> 16);
}

// async global->LDS, 16 B per lane; LDS dest = base + lane*16 (wave-uniform base)
__device__ __forceinline__ void load_lds16(const u16* g, u16* l) {
    __builtin_amdgcn_global_load_lds(
        (const __attribute__((address_space(1))) u32*)g,
        (__attribute__((address_space(3))) u32*)l, 16, 0, 0);
}

// manual s_waitcnt vmcnt(N): lgkmcnt=15 (no wait), expcnt=7 (no wait)
template<int N> __device__ __forceinline__ void waitcnt_vm() {
    __builtin_amdgcn_s_waitcnt(0x0F70 | N);
}
__device__ __forceinline__ void raw_barrier() {
    asm volatile("s_barrier" ::: "memory");
}

// ---------------------------------------------------------------------------
// CSR build
// ---------------------------------------------------------------------------
__global__ void count_int_kernel(const int* __restrict__ idx, int* __restrict__ cnt, int n) {
    int i = blockIdx.x * blockDim.x + threadIdx.x;
    if (i < n) atomicAdd(&cnt[idx[i]], 1);
}

__global__ void scan1_kernel(const int* __restrict__ degi, int* __restrict__ starts,
                             int* __restrict__ bsum) {
    __shared__ int s[256];
    int t = threadIdx.x, i = blockIdx.x * 256 + t;
    int v = (i < N_NODES) ? degi[i] : 0;
    s[t] = v; __syncthreads();
    for (int off = 1; off < 256; off <<= 1) {
        int x = (t >= off) ? s[t - off] : 0;
        __syncthreads();
        s[t] += x;
        __syncthreads();
    }
    if (i < N_NODES) starts[i] = s[t] - v;
    if (t == 255) bsum[blockIdx.x] = s[255];
}

__global__ void scan2_kernel(const int* __restrict__ bsum, int* __restrict__ boff,
                             int* __restrict__ starts, int nb) {
    __shared__ int s[256];
    int t = threadIdx.x;
    int v = (t < nb) ? bsum[t] : 0;
    s[t] = v; __syncthreads();
    for (int off = 1; off < 256; off <<= 1) {
        int x = (t >= off) ? s[t - off] : 0;
        __syncthreads();
        s[t] += x;
        __syncthreads();
    }
    if (t < nb) boff[t] = s[t] - v;
    if (t == nb - 1) starts[N_NODES] = s[t];
}

__global__ void scan3_kernel(int* __restrict__ starts, const int* __restrict__ boff) {
    int i = blockIdx.x * 256 + threadIdx.x;
    if (i < N_NODES) starts[i] += boff[blockIdx.x];
}

__global__ void fill_csr_kernel(const int* __restrict__ src, const int* __restrict__ dst,
                                const int* __restrict__ starts, int* __restrict__ cursor,
                                int* __restrict__ csr) {
    int e = blockIdx.x * blockDim.x + threadIdx.x;
    if (e >= N_EDGES) return;
    int d = dst[e];
    int p = atomicAdd(&cursor[d], 1);
    csr[starts[d] + p] = src[e];
}

__global__ void gstart_kernel(const int* __restrict__ batch, int* __restrict__ gstart) {
    int i = blockIdx.x * blockDim.x + threadIdx.x;
    if (i >= N_NODES) return;
    int b = batch[i];
    int bp = (i == 0) ? -1 : batch[i - 1];
    for (int g = bp + 1; g <= b; ++g) gstart[g] = i;
    if (i == N_NODES - 1)
        for (int g = b + 1; g <= N_GRAPHS; ++g) gstart[g] = N_NODES;
}

__global__ void cntinv_kernel(const int* __restrict__ gstart, float* __restrict__ cntinv) {
    int g = blockIdx.x * blockDim.x + threadIdx.x;
    if (g < N_GRAPHS) cntinv[g] = 1.0f / fmaxf((float)(gstart[g + 1] - gstart[g]), 1.0f);
}

// ---------------------------------------------------------------------------
// conversions
// ---------------------------------------------------------------------------
__global__ void conv_x_kernel(const float* __restrict__ x, u16* __restrict__ abuf1) {
    int i = blockIdx.x * blockDim.x + threadIdx.x;
    if (i >= N_NODES * 64) return;
    int n = i >> 6, c = i & 63;
    float v = (c < 50) ? x[n * 50 + c] : 0.0f;
    abuf1[(size_t)n * 128 + 64 + c] = f2bf(v);
}

template<int DIN, int DINP, int DOUT>
__global__ void conv_w_kernel(const float* __restrict__ Wl, const float* __restrict__ Wr,
                              u16* __restrict__ wbuf) {
    int i = blockIdx.x * blockDim.x + threadIdx.x;
    if (i >= DOUT * DINP) return;
    int o = i / DINP, c = i % DINP;
    float vl = (c < DIN) ? Wl[o * DIN + c] : 0.0f;
    float vr = (c < DIN) ? Wr[o * DIN + c] : 0.0f;
    wbuf[(size_t)o * 2 * DINP + c] = f2bf(vl);
    wbuf[(size_t)o * 2 * DINP + DINP + c] = f2bf(vr);
}

// ---------------------------------------------------------------------------
// CSR gather mean-aggregation, one wave per node, unroll-8 edge prefetch
// ---------------------------------------------------------------------------
template<int DINP>
__global__ __launch_bounds__(256) void csr_agg_kernel(const int* __restrict__ starts,
                                                      const int* __restrict__ csr,
                                                      u16* __restrict__ abuf) {
    constexpr int STRIDE = 2 * DINP;
    constexpr int C = (DINP >= 256) ? 4 : (DINP >= 128 ? 2 : 1);
    int wave = threadIdx.x >> 6, lane = threadIdx.x & 63;
    int n = blockIdx.x * 4 + wave;
    if (n >= N_NODES) return;
    int s0 = starts[n], s1 = starts[n + 1];
    float acc[C];
    #pragma unroll
    for (int c = 0; c < C; ++c) acc[c] = 0.0f;
    const u16* xin = abuf + DINP;

    auto accum = [&](int sidx) {
        const u16* p = xin + (size_t)sidx * STRIDE + lane * C;
        if constexpr (C == 1) {
            acc[0] += bf2f(p[0]);
        } else if constexpr (C == 2) {
            ushort2 u = *(const ushort2*)p;
            acc[0] += bf2f(u.x); acc[1] += bf2f(u.y);
        } else {
            ushort4 u = *(const ushort4*)p;
            acc[0] += bf2f(u.x); acc[1] += bf2f(u.y);
            acc[2] += bf2f(u.z); acc[3] += bf2f(u.w);
        }
    };

    int e = s0;
    for (; e + 8 <= s1; e += 8) {
        int i0 = csr[e],     i1 = csr[e + 1], i2 = csr[e + 2], i3 = csr[e + 3];
        int i4 = csr[e + 4], i5 = csr[e + 5], i6 = csr[e + 6], i7 = csr[e + 7];
        accum(i0); accum(i1); accum(i2); accum(i3);
        accum(i4); accum(i5); accum(i6); accum(i7);
    }
    for (; e < s1; ++e) accum(csr[e]);

    float sc = 1.0f / fmaxf((float)(s1 - s0), 1.0f);
    u16* o = abuf + (size_t)n * STRIDE + lane * C;
    #pragma unroll
    for (int c = 0; c < C; ++c) o[c] = f2bf(acc[c] * sc);
}

// ---------------------------------------------------------------------------
// bf16 MFMA GEMM, AITER-style pipelined staging:
//  - 3-deep LDS ring buffers, global_load_lds(16B), depth-2 prefetch
//  - raw s_barrier + manual s_waitcnt vmcnt(8/4/0): prefetch loads stay in
//    flight ACROSS the barrier (avoids the compiler's vmcnt(0) drain)
//  - XCD-chunked swizzle: each XCD owns a contiguous m-range, n-fastest
//    inside, so blocks sharing an A-tile hit the same XCD's L2.
// 128x128 tile, 4 waves 2x2, 4x4 mfma_16x16x32 per wave.
// ACT 0: leaky_relu, 1: relu.  MODE 0: store bf16.  MODE 1: pool atomicAdd.
// ---------------------------------------------------------------------------
template<int K, int NB, int ACT, int MODE>
__global__ __launch_bounds__(256) void gemm_bf16_kernel(
    const u16* __restrict__ A, const u16* __restrict__ W,
    const float* __restrict__ bias,
    u16* __restrict__ out, int outStride, int outOff,
    float* __restrict__ pool, const int* __restrict__ batch, int N)
{
    constexpr int NKB = K / 32;
    constexpr int MT = M_PAD / 128;          // 391 m-tiles
    constexpr int MCHUNK = (MT + 7) / 8;     // 49 per XCD
    __shared__ __align__(16) u16 As[3][128 * 32];
    __shared__ __align__(16) u16 Bs[3][128 * 32];

    // swizzle: xcd-major m-chunks, n-fastest within
    const int bx = blockIdx.x;
    const int xcd = bx & 7;
    const int seq = bx >> 3;
    const int n = seq % NB;
    const int m = xcd * MCHUNK + seq / NB;
    if (m >= MT) return;
    const int bm = m * 128;
    const int bn = n * 128;

    const int tid = threadIdx.x;
    const int wave = tid >> 6, lane = tid & 63;
    const int wm = (wave & 1) * 64, wn = (wave >> 1) * 64;
    const int lm = lane & 15, lq = lane >> 4;

    // staging: wave w covers rows w*32..w*32+31 of both A and B tiles
    const int srow = wave * 32 + (lane >> 2);
    const int scol = (lane & 3) * 8;
    const u16* gA = A + (size_t)(bm + srow) * K + scol;
    const u16* gB = W + (size_t)(bn + srow) * K + scol;
    const int lbase = wave * 32 * 32;

    auto stage = [&](int s, int r) {
        const int ko = s * 32;
        load_lds16(gA + ko,                    &As[r][lbase]);
        load_lds16(gA + (size_t)16 * K + ko,   &As[r][lbase + 16 * 32]);
        load_lds16(gB + ko,                    &Bs[r][lbase]);
        load_lds16(gB + (size_t)16 * K + ko,   &Bs[r][lbase + 16 * 32]);
    };

    floatx4 acc[4][4] = {};

    // prologue: two slabs in flight
    stage(0, 0);
    stage(1, 1);

    #pragma unroll
    for (int kb = 0; kb < NKB; ++kb) {
        if (kb + 2 < NKB) stage(kb + 2, (kb + 2) % 3);
        // wait for slab kb only; leave up to 2 future slabs (8 loads) in flight
        const int rem = NKB - 1 - kb;
        if (rem >= 2)      waitcnt_vm<8>();
        else if (rem == 1) waitcnt_vm<4>();
        else               waitcnt_vm<0>();
        raw_barrier();

        const int r = kb % 3;
        bf16x8 af[4], bfr[4];
        #pragma unroll
        for (int mi = 0; mi < 4; ++mi)
            af[mi] = *(const bf16x8*)&As[r][(wm + mi * 16 + lm) * 32 + lq * 8];
        #pragma unroll
        for (int ni = 0; ni < 4; ++ni)
            bfr[ni] = *(const bf16x8*)&Bs[r][(wn + ni * 16 + lm) * 32 + lq * 8];
        #pragma unroll
        for (int mi = 0; mi < 4; ++mi)
            #pragma unroll
            for (int ni = 0; ni < 4; ++ni)
                acc[mi][ni] = __builtin_amdgcn_mfma_f32_16x16x32_bf16(
                    af[mi], bfr[ni], acc[mi][ni], 0, 0, 0);
        raw_barrier();   // all waves done reading ring slot r before it is re-staged
    }

    // epilogue: D row=node (bm+wm+mi*16+lq*4+r), col=o (bn+wn+ni*16+lm)
    #pragma unroll
    for (int mi = 0; mi < 4; ++mi) {
        int node0 = bm + wm + mi * 16 + lq * 4;
        int b0 = -1, b3 = -2;
        if (MODE == 1) {
            b0 = (node0 < N) ? batch[node0] : -1;
            b3 = (node0 + 3 < N) ? batch[node0 + 3] : -2;
        }
        #pragma unroll
        for (int ni = 0; ni < 4; ++ni) {
            int o = bn + wn + ni * 16 + lm;
            float bi = bias[o];
            if (MODE == 0) {
                #pragma unroll
                for (int r = 0; r < 4; ++r) {
                    int node = node0 + r;
                    if (node >= N) continue;
                    float v = acc[mi][ni][r] + bi;
                    if (ACT == 0) v = (v > 0.0f) ? v : 0.01f * v;
                    else          v = fmaxf(v, 0.0f);
                    out[(size_t)node * outStride + outOff + o] = f2bf(v);
                }
            } else {
                float v[4];
                #pragma unroll
                for (int r = 0; r < 4; ++r)
                    v[r] = (node0 + r < N) ? fmaxf(acc[mi][ni][r] + bi, 0.0f) : 0.0f;
                if (b0 == b3) {
                    atomicAdd(&pool[(size_t)b0 * 512 + o], v[0] + v[1] + v[2] + v[3]);
                } else {
                    for (int r = 0; r < 4; ++r)
                        if (node0 + r < N)
                            atomicAdd(&pool[(size_t)batch[node0 + r] * 512 + o], v[r]);
                }
            }
        }
    }
}

// ---------------------------------------------------------------------------
// small dense layers over 512 graph rows (fp32 head)
// ---------------------------------------------------------------------------
template<int DIN, int DOUT, int ACT>
__global__ void dense_small_kernel(const float* __restrict__ X,
                                   const float* __restrict__ W,
                                   const float* __restrict__ b,
                                   const float* __restrict__ scale,
                                   float* __restrict__ Y)
{
    __shared__ float xs[DIN];
    const int g = blockIdx.x;
    const float sc = scale ? scale[g] : 1.0f;
    for (int k = threadIdx.x; k < DIN; k += blockDim.x)
        xs[k] = X[g * DIN + k] * sc;
    __syncthreads();
    for (int o = threadIdx.x; o < DOUT; o += blockDim.x) {
        float s = b[o];
        #pragma unroll 4
        for (int k = 0; k < DIN; ++k) s += xs[k] * W[o * DIN + k];
        if (ACT == 1) s = fmaxf(s, 0.0f);
        if (ACT == 2) s = 1.0f / (1.0f + expf(-s));
        Y[g * DOUT + o] = s;
    }
}

// ---------------------------------------------------------------------------
extern "C" void kernel_launch(void* const* d_in, const int* in_sizes, int n_in,
                              void* d_out, int out_size, void* d_ws, size_t ws_size,
                              hipStream_t stream)
{
    const float* x     = (const float*)d_in[0];
    const int*   ei    = (const int*)  d_in[1];
    const int*   batch = (const int*)  d_in[2];
    const float* Wl1   = (const float*)d_in[3];
    const float* bl1   = (const float*)d_in[4];
    const float* Wr1   = (const float*)d_in[5];
    const float* Wl2   = (const float*)d_in[6];
    const float* bl2   = (const float*)d_in[7];
    const float* Wr2   = (const float*)d_in[8];
    const float* Wl3   = (const float*)d_in[9];
    const float* bl3   = (const float*)d_in[10];
    const float* Wr3   = (const float*)d_in[11];
    const float* Wf1   = (const float*)d_in[12];
    const float* bf1   = (const float*)d_in[13];
    const float* Wf2   = (const float*)d_in[14];
    const float* bf2   = (const float*)d_in[15];
    const float* Wo    = (const float*)d_in[16];
    const float* bo    = (const float*)d_in[17];

    const int* src = ei;
    const int* dst = ei + N_EDGES;

    char* p = (char*)d_ws;
    auto alloc = [&](size_t bytes) { char* r = p; p += (bytes + 255) & ~(size_t)255; return r; };
    int*   degi   = (int*)  alloc(50176 * 4);
    int*   starts = (int*)  alloc(50432 * 4);
    int*   bsum   = (int*)  alloc(256 * 4);
    int*   boff   = (int*)  alloc(256 * 4);
    int*   cursor = (int*)  alloc(50176 * 4);
    int*   csr    = (int*)  alloc((size_t)N_EDGES * 4);
    int*   gstart = (int*)  alloc(513 * 4);
    float* cntinv = (float*)alloc(512 * 4);
    float* pool   = (float*)alloc((size_t)512 * 512 * 4);
    float* x4     = (float*)alloc((size_t)512 * 256 * 4);
    float* x5     = (float*)alloc((size_t)512 * 128 * 4);
    u16*   abuf1  = (u16*)  alloc((size_t)M_PAD * 128 * 2);
    u16*   abuf2  = (u16*)  alloc((size_t)M_PAD * 256 * 2);
    u16*   abuf3  = (u16*)  alloc((size_t)M_PAD * 512 * 2);
    u16*   wb1    = (u16*)  alloc((size_t)128 * 128 * 2);
    u16*   wb2    = (u16*)  alloc((size_t)256 * 256 * 2);
    u16*   wb3    = (u16*)  alloc((size_t)512 * 512 * 2);

    // ---- CSR build ----
    hipMemsetAsync(degi, 0, 50176 * 4, stream);
    hipMemsetAsync(cursor, 0, 50176 * 4, stream);
    count_int_kernel<<<(N_EDGES + 255) / 256, 256, 0, stream>>>(dst, degi, N_EDGES);
    scan1_kernel<<<196, 256, 0, stream>>>(degi, starts, bsum);
    scan2_kernel<<<1, 256, 0, stream>>>(bsum, boff, starts, 196);
    scan3_kernel<<<196, 256, 0, stream>>>(starts, boff);
    fill_csr_kernel<<<(N_EDGES + 255) / 256, 256, 0, stream>>>(src, dst, starts, cursor, csr);
    gstart_kernel<<<196, 256, 0, stream>>>(batch, gstart);
    cntinv_kernel<<<2, 256, 0, stream>>>(gstart, cntinv);

    // ---- conversions ----
    conv_x_kernel<<<(N_NODES * 64 + 255) / 256, 256, 0, stream>>>(x, abuf1);
    conv_w_kernel<50, 64, 128><<<(128 * 64 + 255) / 256, 256, 0, stream>>>(Wl1, Wr1, wb1);
    conv_w_kernel<128, 128, 256><<<(256 * 128 + 255) / 256, 256, 0, stream>>>(Wl2, Wr2, wb2);
    conv_w_kernel<256, 256, 512><<<(512 * 256 + 255) / 256, 256, 0, stream>>>(Wl3, Wr3, wb3);

    const int GB = 12500;
    const int GEMM_GRID = 49 * 8;   // MCHUNK * 8 XCDs (x NB)

    // ---- layer 1: 50 -> 128, leaky_relu ----
    csr_agg_kernel<64><<<GB, 256, 0, stream>>>(starts, csr, abuf1);
    gemm_bf16_kernel<128, 1, 0, 0><<<GEMM_GRID * 1, 256, 0, stream>>>(
        abuf1, wb1, bl1, abuf2, 256, 128, nullptr, nullptr, N_NODES);

    // ---- layer 2: 128 -> 256, relu ----
    csr_agg_kernel<128><<<GB, 256, 0, stream>>>(starts, csr, abuf2);
    gemm_bf16_kernel<256, 2, 1, 0><<<GEMM_GRID * 2, 256, 0, stream>>>(
        abuf2, wb2, bl2, abuf3, 512, 256, nullptr, nullptr, N_NODES);

    // ---- layer 3: 256 -> 512, relu + fused pool sum ----
    csr_agg_kernel<256><<<GB, 256, 0, stream>>>(starts, csr, abuf3);
    hipMemsetAsync(pool, 0, (size_t)512 * 512 * 4, stream);
    gemm_bf16_kernel<512, 4, 1, 1><<<GEMM_GRID * 4, 256, 0, stream>>>(
        abuf3, wb3, bl3, nullptr, 0, 0, pool, batch, N_NODES);

    // ---- MLP head (fp32) ----
    dense_small_kernel<512, 256, 1><<<N_GRAPHS, 256, 0, stream>>>(pool, Wf1, bf1, cntinv, x4);
    dense_small_kernel<256, 128, 1><<<N_GRAPHS, 128, 0, stream>>>(x4, Wf2, bf2, nullptr, x5);
    dense_small_kernel<128, 1, 2><<<N_GRAPHS, 64, 0, stream>>>(x5, Wo, bo, nullptr, (float*)d_out);
}

// Round 6
// 486.396 us; speedup vs baseline: 1.2601x; 1.0704x over previous
//
#include <hip/hip_runtime.h>
#include <math.h>

#define N_NODES 50000
#define N_EDGES 800000
#define N_GRAPHS 512
#define M_PAD 50048   // N_NODES rounded up to 128

typedef unsigned short u16;
typedef unsigned int u32;
using bf16x8 = __attribute__((ext_vector_type(8))) short;
using floatx4 = __attribute__((ext_vector_type(4))) float;

__device__ __forceinline__ float bf2f(u16 h) {
    union { u32 u; float f; } v; v.u = ((u32)h) << 16; return v.f;
}
__device__ __forceinline__ u16 f2bf(float f) {
    union { float f; u32 u; } v; v.f = f;
    u32 u = v.u;
    return (u16)((u + 0x7FFFu + ((u >> 16) & 1u)) >> 16);
}

// async global->LDS, 16 B per lane; LDS dest = base + lane*16 (wave-uniform base)
__device__ __forceinline__ void load_lds16(const u16* g, u16* l) {
    __builtin_amdgcn_global_load_lds(
        (const __attribute__((address_space(1))) u32*)g,
        (__attribute__((address_space(3))) u32*)l, 16, 0, 0);
}

// manual s_waitcnt vmcnt(N): lgkmcnt=15 (no wait), expcnt=7 (no wait)
template<int N> __device__ __forceinline__ void waitcnt_vm() {
    __builtin_amdgcn_s_waitcnt(0x0F70 | N);
}
__device__ __forceinline__ void raw_barrier() {
    asm volatile("s_barrier" ::: "memory");
}

// ---------------------------------------------------------------------------
// CSR build
// ---------------------------------------------------------------------------
__global__ void count_int_kernel(const int* __restrict__ idx, int* __restrict__ cnt, int n) {
    int i = blockIdx.x * blockDim.x + threadIdx.x;
    if (i < n) atomicAdd(&cnt[idx[i]], 1);
}

__global__ void scan1_kernel(const int* __restrict__ degi, int* __restrict__ starts,
                             int* __restrict__ bsum) {
    __shared__ int s[256];
    int t = threadIdx.x, i = blockIdx.x * 256 + t;
    int v = (i < N_NODES) ? degi[i] : 0;
    s[t] = v; __syncthreads();
    for (int off = 1; off < 256; off <<= 1) {
        int x = (t >= off) ? s[t - off] : 0;
        __syncthreads();
        s[t] += x;
        __syncthreads();
    }
    if (i < N_NODES) starts[i] = s[t] - v;
    if (t == 255) bsum[blockIdx.x] = s[255];
}

__global__ void scan2_kernel(const int* __restrict__ bsum, int* __restrict__ boff,
                             int* __restrict__ starts, int nb) {
    __shared__ int s[256];
    int t = threadIdx.x;
    int v = (t < nb) ? bsum[t] : 0;
    s[t] = v; __syncthreads();
    for (int off = 1; off < 256; off <<= 1) {
        int x = (t >= off) ? s[t - off] : 0;
        __syncthreads();
        s[t] += x;
        __syncthreads();
    }
    if (t < nb) boff[t] = s[t] - v;
    if (t == nb - 1) starts[N_NODES] = s[t];
}

__global__ void scan3_kernel(int* __restrict__ starts, const int* __restrict__ boff) {
    int i = blockIdx.x * 256 + threadIdx.x;
    if (i < N_NODES) starts[i] += boff[blockIdx.x];
}

__global__ void fill_csr_kernel(const int* __restrict__ src, const int* __restrict__ dst,
                                const int* __restrict__ starts, int* __restrict__ cursor,
                                int* __restrict__ csr) {
    int e = blockIdx.x * blockDim.x + threadIdx.x;
    if (e >= N_EDGES) return;
    int d = dst[e];
    int p = atomicAdd(&cursor[d], 1);
    csr[starts[d] + p] = src[e];
}

__global__ void gstart_kernel(const int* __restrict__ batch, int* __restrict__ gstart) {
    int i = blockIdx.x * blockDim.x + threadIdx.x;
    if (i >= N_NODES) return;
    int b = batch[i];
    int bp = (i == 0) ? -1 : batch[i - 1];
    for (int g = bp + 1; g <= b; ++g) gstart[g] = i;
    if (i == N_NODES - 1)
        for (int g = b + 1; g <= N_GRAPHS; ++g) gstart[g] = N_NODES;
}

__global__ void cntinv_kernel(const int* __restrict__ gstart, float* __restrict__ cntinv) {
    int g = blockIdx.x * blockDim.x + threadIdx.x;
    if (g < N_GRAPHS) cntinv[g] = 1.0f / fmaxf((float)(gstart[g + 1] - gstart[g]), 1.0f);
}

// ---------------------------------------------------------------------------
// conversions
// ---------------------------------------------------------------------------
__global__ void conv_x_kernel(const float* __restrict__ x, u16* __restrict__ abuf1) {
    int i = blockIdx.x * blockDim.x + threadIdx.x;
    if (i >= N_NODES * 64) return;
    int n = i >> 6, c = i & 63;
    float v = (c < 50) ? x[n * 50 + c] : 0.0f;
    abuf1[(size_t)n * 128 + 64 + c] = f2bf(v);
}

template<int DIN, int DINP, int DOUT>
__global__ void conv_w_kernel(const float* __restrict__ Wl, const float* __restrict__ Wr,
                              u16* __restrict__ wbuf) {
    int i = blockIdx.x * blockDim.x + threadIdx.x;
    if (i >= DOUT * DINP) return;
    int o = i / DINP, c = i % DINP;
    float vl = (c < DIN) ? Wl[o * DIN + c] : 0.0f;
    float vr = (c < DIN) ? Wr[o * DIN + c] : 0.0f;
    wbuf[(size_t)o * 2 * DINP + c] = f2bf(vl);
    wbuf[(size_t)o * 2 * DINP + DINP + c] = f2bf(vr);
}

// ---------------------------------------------------------------------------
// CSR gather mean-aggregation: multi-edge-per-wave.
// Row payload = DINP u16 = DINP*2 bytes; LPR lanes x 16B cover one row;
// EPW = 64/LPR edges processed per wave-iteration; cross-sub shfl reduce.
// ---------------------------------------------------------------------------
template<int DINP>
__global__ __launch_bounds__(256) void csr_agg_kernel(const int* __restrict__ starts,
                                                      const int* __restrict__ csr,
                                                      u16* __restrict__ abuf) {
    constexpr int STRIDE = 2 * DINP;            // u16 per node row
    constexpr int LPR = (DINP * 2) / 16;        // lanes per row: 8 / 16 / 32
    constexpr int EPW = 64 / LPR;               // edges per wave iter: 8 / 4 / 2
    constexpr int U = (EPW == 2) ? 4 : 2;       // manual unroll depth
    const int wave = threadIdx.x >> 6, lane = threadIdx.x & 63;
    const int n = blockIdx.x * 4 + wave;
    if (n >= N_NODES) return;
    const int sub = lane / LPR;
    const int li = lane % LPR;
    const int s0 = starts[n], s1 = starts[n + 1];

    float acc[8] = {};
    const u16* xin = abuf + DINP;

    int e = s0 + sub;
    for (; e + (U - 1) * EPW < s1; e += U * EPW) {
        int idx[U];
        uint4 u[U];
        #pragma unroll
        for (int j = 0; j < U; ++j) idx[j] = csr[e + j * EPW];
        #pragma unroll
        for (int j = 0; j < U; ++j)
            u[j] = *(const uint4*)(xin + (size_t)idx[j] * STRIDE + li * 8);
        #pragma unroll
        for (int j = 0; j < U; ++j) {
            const u16* h = (const u16*)&u[j];
            #pragma unroll
            for (int c = 0; c < 8; ++c) acc[c] += bf2f(h[c]);
        }
    }
    for (; e < s1; e += EPW) {
        int sidx = csr[e];
        uint4 u = *(const uint4*)(xin + (size_t)sidx * STRIDE + li * 8);
        const u16* h = (const u16*)&u;
        #pragma unroll
        for (int c = 0; c < 8; ++c) acc[c] += bf2f(h[c]);
    }

    // cross-sub reduce: fold 64 lanes down to LPR lanes
    #pragma unroll
    for (int off = 32; off >= LPR; off >>= 1) {
        #pragma unroll
        for (int c = 0; c < 8; ++c) acc[c] += __shfl_down(acc[c], off);
    }

    if (sub == 0) {
        float sc = 1.0f / fmaxf((float)(s1 - s0), 1.0f);
        u16 o16[8];
        #pragma unroll
        for (int c = 0; c < 8; ++c) o16[c] = f2bf(acc[c] * sc);
        *(uint4*)(abuf + (size_t)n * STRIDE + li * 8) = *(const uint4*)o16;
    }
}

// ---------------------------------------------------------------------------
// bf16 MFMA GEMM (R5 core): 3-deep LDS ring, global_load_lds(16B), raw
// s_barrier + manual vmcnt so prefetches stay in flight across barriers,
// XCD-chunked swizzle. 128x128 tile, 4 waves 2x2, 4x4 mfma_16x16x32.
// Plain bf16 store epilogue (NO atomics). ACT 0: leaky_relu, 1: relu.
// ---------------------------------------------------------------------------
template<int K, int NB, int ACT>
__global__ __launch_bounds__(256) void gemm_bf16_kernel(
    const u16* __restrict__ A, const u16* __restrict__ W,
    const float* __restrict__ bias,
    u16* __restrict__ out, int outStride, int outOff, int N)
{
    constexpr int NKB = K / 32;
    constexpr int MT = M_PAD / 128;          // 391 m-tiles
    constexpr int MCHUNK = (MT + 7) / 8;     // 49 per XCD
    __shared__ __align__(16) u16 As[3][128 * 32];
    __shared__ __align__(16) u16 Bs[3][128 * 32];

    const int bx = blockIdx.x;
    const int xcd = bx & 7;
    const int seq = bx >> 3;
    const int n = seq % NB;
    const int m = xcd * MCHUNK + seq / NB;
    if (m >= MT) return;
    const int bm = m * 128;
    const int bn = n * 128;

    const int tid = threadIdx.x;
    const int wave = tid >> 6, lane = tid & 63;
    const int wm = (wave & 1) * 64, wn = (wave >> 1) * 64;
    const int lm = lane & 15, lq = lane >> 4;

    const int srow = wave * 32 + (lane >> 2);
    const int scol = (lane & 3) * 8;
    const u16* gA = A + (size_t)(bm + srow) * K + scol;
    const u16* gB = W + (size_t)(bn + srow) * K + scol;
    const int lbase = wave * 32 * 32;

    auto stage = [&](int s, int r) {
        const int ko = s * 32;
        load_lds16(gA + ko,                  &As[r][lbase]);
        load_lds16(gA + (size_t)16 * K + ko, &As[r][lbase + 16 * 32]);
        load_lds16(gB + ko,                  &Bs[r][lbase]);
        load_lds16(gB + (size_t)16 * K + ko, &Bs[r][lbase + 16 * 32]);
    };

    floatx4 acc[4][4] = {};

    stage(0, 0);
    stage(1, 1);

    #pragma unroll
    for (int kb = 0; kb < NKB; ++kb) {
        if (kb + 2 < NKB) stage(kb + 2, (kb + 2) % 3);
        const int rem = NKB - 1 - kb;
        if (rem >= 2)      waitcnt_vm<8>();
        else if (rem == 1) waitcnt_vm<4>();
        else               waitcnt_vm<0>();
        raw_barrier();

        const int r = kb % 3;
        bf16x8 af[4], bfr[4];
        #pragma unroll
        for (int mi = 0; mi < 4; ++mi)
            af[mi] = *(const bf16x8*)&As[r][(wm + mi * 16 + lm) * 32 + lq * 8];
        #pragma unroll
        for (int ni = 0; ni < 4; ++ni)
            bfr[ni] = *(const bf16x8*)&Bs[r][(wn + ni * 16 + lm) * 32 + lq * 8];
        #pragma unroll
        for (int mi = 0; mi < 4; ++mi)
            #pragma unroll
            for (int ni = 0; ni < 4; ++ni)
                acc[mi][ni] = __builtin_amdgcn_mfma_f32_16x16x32_bf16(
                    af[mi], bfr[ni], acc[mi][ni], 0, 0, 0);
        raw_barrier();
    }

    // epilogue: D row=node (bm+wm+mi*16+lq*4+r), col=o (bn+wn+ni*16+lm)
    #pragma unroll
    for (int mi = 0; mi < 4; ++mi) {
        int node0 = bm + wm + mi * 16 + lq * 4;
        #pragma unroll
        for (int ni = 0; ni < 4; ++ni) {
            int o = bn + wn + ni * 16 + lm;
            float bi = bias[o];
            #pragma unroll
            for (int r = 0; r < 4; ++r) {
                int node = node0 + r;
                if (node >= N) continue;
                float v = acc[mi][ni][r] + bi;
                if (ACT == 0) v = (v > 0.0f) ? v : 0.01f * v;
                else          v = fmaxf(v, 0.0f);
                out[(size_t)node * outStride + outOff + o] = f2bf(v);
            }
        }
    }
}

// ---------------------------------------------------------------------------
// global mean pool: one block per graph, segment sum (batch sorted, NO atomics)
// ---------------------------------------------------------------------------
__global__ __launch_bounds__(256) void pool_kernel(const u16* __restrict__ x3,
                                                   const int* __restrict__ gstart,
                                                   const float* __restrict__ cntinv,
                                                   float* __restrict__ pool) {
    const int g = blockIdx.x;
    const int c2 = threadIdx.x * 2;
    const int n0 = gstart[g], n1 = gstart[g + 1];
    float a0 = 0.0f, a1 = 0.0f;
    for (int n = n0; n < n1; ++n) {
        ushort2 u = *(const ushort2*)(x3 + (size_t)n * 512 + c2);
        a0 += bf2f(u.x); a1 += bf2f(u.y);
    }
    const float sc = cntinv[g];
    pool[(size_t)g * 512 + c2]     = a0 * sc;
    pool[(size_t)g * 512 + c2 + 1] = a1 * sc;
}

// ---------------------------------------------------------------------------
// small dense layers over 512 graph rows (fp32 head)
// ---------------------------------------------------------------------------
template<int DIN, int DOUT, int ACT>
__global__ void dense_small_kernel(const float* __restrict__ X,
                                   const float* __restrict__ W,
                                   const float* __restrict__ b,
                                   float* __restrict__ Y)
{
    __shared__ float xs[DIN];
    const int g = blockIdx.x;
    for (int k = threadIdx.x; k < DIN; k += blockDim.x)
        xs[k] = X[g * DIN + k];
    __syncthreads();
    for (int o = threadIdx.x; o < DOUT; o += blockDim.x) {
        float s = b[o];
        #pragma unroll 4
        for (int k = 0; k < DIN; ++k) s += xs[k] * W[o * DIN + k];
        if (ACT == 1) s = fmaxf(s, 0.0f);
        if (ACT == 2) s = 1.0f / (1.0f + expf(-s));
        Y[g * DOUT + o] = s;
    }
}

// ---------------------------------------------------------------------------
extern "C" void kernel_launch(void* const* d_in, const int* in_sizes, int n_in,
                              void* d_out, int out_size, void* d_ws, size_t ws_size,
                              hipStream_t stream)
{
    const float* x     = (const float*)d_in[0];
    const int*   ei    = (const int*)  d_in[1];
    const int*   batch = (const int*)  d_in[2];
    const float* Wl1   = (const float*)d_in[3];
    const float* bl1   = (const float*)d_in[4];
    const float* Wr1   = (const float*)d_in[5];
    const float* Wl2   = (const float*)d_in[6];
    const float* bl2   = (const float*)d_in[7];
    const float* Wr2   = (const float*)d_in[8];
    const float* Wl3   = (const float*)d_in[9];
    const float* bl3   = (const float*)d_in[10];
    const float* Wr3   = (const float*)d_in[11];
    const float* Wf1   = (const float*)d_in[12];
    const float* bf1   = (const float*)d_in[13];
    const float* Wf2   = (const float*)d_in[14];
    const float* bf2   = (const float*)d_in[15];
    const float* Wo    = (const float*)d_in[16];
    const float* bo    = (const float*)d_in[17];

    const int* src = ei;
    const int* dst = ei + N_EDGES;

    // ---- workspace layout ----
    // persistent region (alive through the whole call):
    char* p = (char*)d_ws;
    auto alloc = [&](size_t bytes) { char* r = p; p += (bytes + 255) & ~(size_t)255; return r; };
    int*   gstart = (int*)  alloc(513 * 4);
    float* cntinv = (float*)alloc(512 * 4);
    float* pool   = (float*)alloc((size_t)512 * 512 * 4);
    float* x4     = (float*)alloc((size_t)512 * 256 * 4);
    float* x5     = (float*)alloc((size_t)512 * 128 * 4);
    u16*   abuf3  = (u16*)  alloc((size_t)M_PAD * 512 * 2);
    u16*   wb3    = (u16*)  alloc((size_t)512 * 512 * 2);
    // union region: phase A (CSR + early layers) vs phase B (x3 output)
    char* ubase = p;
    int*   degi   = (int*)  alloc(50176 * 4);
    int*   starts = (int*)  alloc(50432 * 4);
    int*   bsum   = (int*)  alloc(256 * 4);
    int*   boff   = (int*)  alloc(256 * 4);
    int*   cursor = (int*)  alloc(50176 * 4);
    int*   csr    = (int*)  alloc((size_t)N_EDGES * 4);
    u16*   abuf1  = (u16*)  alloc((size_t)M_PAD * 128 * 2);
    u16*   abuf2  = (u16*)  alloc((size_t)M_PAD * 256 * 2);
    u16*   wb1    = (u16*)  alloc((size_t)128 * 128 * 2);
    u16*   wb2    = (u16*)  alloc((size_t)256 * 256 * 2);
    // phase B: x3 (51.2 MB) overlays phase A (~43 MB used above + slack)
    u16*   x3buf  = (u16*)ubase;

    // ---- CSR build ----
    hipMemsetAsync(degi, 0, 50176 * 4, stream);
    hipMemsetAsync(cursor, 0, 50176 * 4, stream);
    count_int_kernel<<<(N_EDGES + 255) / 256, 256, 0, stream>>>(dst, degi, N_EDGES);
    scan1_kernel<<<196, 256, 0, stream>>>(degi, starts, bsum);
    scan2_kernel<<<1, 256, 0, stream>>>(bsum, boff, starts, 196);
    scan3_kernel<<<196, 256, 0, stream>>>(starts, boff);
    fill_csr_kernel<<<(N_EDGES + 255) / 256, 256, 0, stream>>>(src, dst, starts, cursor, csr);
    gstart_kernel<<<196, 256, 0, stream>>>(batch, gstart);
    cntinv_kernel<<<2, 256, 0, stream>>>(gstart, cntinv);

    // ---- conversions ----
    conv_x_kernel<<<(N_NODES * 64 + 255) / 256, 256, 0, stream>>>(x, abuf1);
    conv_w_kernel<50, 64, 128><<<(128 * 64 + 255) / 256, 256, 0, stream>>>(Wl1, Wr1, wb1);
    conv_w_kernel<128, 128, 256><<<(256 * 128 + 255) / 256, 256, 0, stream>>>(Wl2, Wr2, wb2);
    conv_w_kernel<256, 256, 512><<<(512 * 256 + 255) / 256, 256, 0, stream>>>(Wl3, Wr3, wb3);

    const int GB = 12500;
    const int GEMM_GRID = 49 * 8;   // MCHUNK * 8 XCDs (x NB)

    // ---- layer 1: 50 -> 128, leaky_relu ----
    csr_agg_kernel<64><<<GB, 256, 0, stream>>>(starts, csr, abuf1);
    gemm_bf16_kernel<128, 1, 0><<<GEMM_GRID * 1, 256, 0, stream>>>(
        abuf1, wb1, bl1, abuf2, 256, 128, N_NODES);

    // ---- layer 2: 128 -> 256, relu ----
    csr_agg_kernel<128><<<GB, 256, 0, stream>>>(starts, csr, abuf2);
    gemm_bf16_kernel<256, 2, 1><<<GEMM_GRID * 2, 256, 0, stream>>>(
        abuf2, wb2, bl2, abuf3, 512, 256, N_NODES);

    // ---- layer 3: 256 -> 512, relu -> x3 (bf16), then pool (no atomics) ----
    csr_agg_kernel<256><<<GB, 256, 0, stream>>>(starts, csr, abuf3);
    gemm_bf16_kernel<512, 4, 1><<<GEMM_GRID * 4, 256, 0, stream>>>(
        abuf3, wb3, bl3, x3buf, 512, 0, N_NODES);
    pool_kernel<<<N_GRAPHS, 256, 0, stream>>>(x3buf, gstart, cntinv, pool);

    // ---- MLP head (fp32) ----
    dense_small_kernel<512, 256, 1><<<N_GRAPHS, 256, 0, stream>>>(pool, Wf1, bf1, x4);
    dense_small_kernel<256, 128, 1><<<N_GRAPHS, 128, 0, stream>>>(x4, Wf2, bf2, x5);
    dense_small_kernel<128, 1, 2><<<N_GRAPHS, 64, 0, stream>>>(x5, Wo, bo, (float*)d_out);
}

// Round 7
// 469.608 us; speedup vs baseline: 1.3051x; 1.0357x over previous
//
#include <hip/hip_runtime.h>
#include <math.h>

#define N_NODES 50000
#define N_EDGES 800000
#define N_GRAPHS 512
#define M_PAD 50048   // N_NODES rounded up to 128

typedef unsigned char u8;
typedef unsigned short u16;
typedef unsigned int u32;
using bf16x8 = __attribute__((ext_vector_type(8))) short;
using floatx4 = __attribute__((ext_vector_type(4))) float;
using floatx2 = __attribute__((ext_vector_type(2))) float;

__device__ __forceinline__ float bf2f(u16 h) {
    union { u32 u; float f; } v; v.u = ((u32)h) << 16; return v.f;
}
__device__ __forceinline__ u16 f2bf(float f) {
    union { float f; u32 u; } v; v.f = f;
    u32 u = v.u;
    return (u16)((u + 0x7FFFu + ((u >> 16) & 1u)) >> 16);
}
// f32 -> OCP e4m3 (single byte via HW pack)
__device__ __forceinline__ u8 f2fp8(float v) {
    return (u8)(__builtin_amdgcn_cvt_pk_fp8_f32(v, v, 0, false) & 0xFF);
}
// pack 4 floats -> 4 fp8 bytes in a u32
__device__ __forceinline__ u32 pack4fp8(float a, float b, float c, float d) {
    u32 p = __builtin_amdgcn_cvt_pk_fp8_f32(a, b, 0, false);
    return __builtin_amdgcn_cvt_pk_fp8_f32(c, d, p, true);
}
// accumulate 16 fp8 (one uint4) into acc[16]
__device__ __forceinline__ void acc16fp8(float* acc, uint4 u) {
    const u32 w[4] = {u.x, u.y, u.z, u.w};
    #pragma unroll
    for (int j = 0; j < 4; ++j) {
        floatx2 lo = __builtin_amdgcn_cvt_pk_f32_fp8((int)w[j], false);
        floatx2 hi = __builtin_amdgcn_cvt_pk_f32_fp8((int)w[j], true);
        acc[j * 4 + 0] += lo[0]; acc[j * 4 + 1] += lo[1];
        acc[j * 4 + 2] += hi[0]; acc[j * 4 + 3] += hi[1];
    }
}

// async global->LDS, 16 B per lane; LDS dest = base + lane*16 (wave-uniform base)
__device__ __forceinline__ void load_lds16(const u16* g, u16* l) {
    __builtin_amdgcn_global_load_lds(
        (const __attribute__((address_space(1))) u32*)g,
        (__attribute__((address_space(3))) u32*)l, 16, 0, 0);
}
template<int N> __device__ __forceinline__ void waitcnt_vm() {
    __builtin_amdgcn_s_waitcnt(0x0F70 | N);
}
__device__ __forceinline__ void raw_barrier() {
    asm volatile("s_barrier" ::: "memory");
}

// ---------------------------------------------------------------------------
// CSR build
// ---------------------------------------------------------------------------
__global__ void count_int_kernel(const int* __restrict__ idx, int* __restrict__ cnt, int n) {
    int i = blockIdx.x * blockDim.x + threadIdx.x;
    if (i < n) atomicAdd(&cnt[idx[i]], 1);
}

__global__ void scan1_kernel(const int* __restrict__ degi, int* __restrict__ starts,
                             int* __restrict__ bsum) {
    __shared__ int s[256];
    int t = threadIdx.x, i = blockIdx.x * 256 + t;
    int v = (i < N_NODES) ? degi[i] : 0;
    s[t] = v; __syncthreads();
    for (int off = 1; off < 256; off <<= 1) {
        int x = (t >= off) ? s[t - off] : 0;
        __syncthreads();
        s[t] += x;
        __syncthreads();
    }
    if (i < N_NODES) starts[i] = s[t] - v;
    if (t == 255) bsum[blockIdx.x] = s[255];
}

__global__ void scan2_kernel(const int* __restrict__ bsum, int* __restrict__ boff,
                             int* __restrict__ starts, int nb) {
    __shared__ int s[256];
    int t = threadIdx.x;
    int v = (t < nb) ? bsum[t] : 0;
    s[t] = v; __syncthreads();
    for (int off = 1; off < 256; off <<= 1) {
        int x = (t >= off) ? s[t - off] : 0;
        __syncthreads();
        s[t] += x;
        __syncthreads();
    }
    if (t < nb) boff[t] = s[t] - v;
    if (t == nb - 1) starts[N_NODES] = s[t];
}

__global__ void scan3_kernel(int* __restrict__ starts, const int* __restrict__ boff) {
    int i = blockIdx.x * 256 + threadIdx.x;
    if (i < N_NODES) starts[i] += boff[blockIdx.x];
}

__global__ void fill_csr_kernel(const int* __restrict__ src, const int* __restrict__ dst,
                                const int* __restrict__ starts, int* __restrict__ cursor,
                                int* __restrict__ csr) {
    int e = blockIdx.x * blockDim.x + threadIdx.x;
    if (e >= N_EDGES) return;
    int d = dst[e];
    int p = atomicAdd(&cursor[d], 1);
    csr[starts[d] + p] = src[e];
}

__global__ void gstart_kernel(const int* __restrict__ batch, int* __restrict__ gstart) {
    int i = blockIdx.x * blockDim.x + threadIdx.x;
    if (i >= N_NODES) return;
    int b = batch[i];
    int bp = (i == 0) ? -1 : batch[i - 1];
    for (int g = bp + 1; g <= b; ++g) gstart[g] = i;
    if (i == N_NODES - 1)
        for (int g = b + 1; g <= N_GRAPHS; ++g) gstart[g] = N_NODES;
}

__global__ void cntinv_kernel(const int* __restrict__ gstart, float* __restrict__ cntinv) {
    int g = blockIdx.x * blockDim.x + threadIdx.x;
    if (g < N_GRAPHS) cntinv[g] = 1.0f / fmaxf((float)(gstart[g + 1] - gstart[g]), 1.0f);
}

// ---------------------------------------------------------------------------
// conversions
// ---------------------------------------------------------------------------
// x -> bf16 xin half of abuf1 AND fp8 gbuf1. Thread = (node, 4 cols).
__global__ void conv_x_kernel(const float* __restrict__ x, u16* __restrict__ abuf1,
                              u8* __restrict__ gbuf1) {
    int i = blockIdx.x * blockDim.x + threadIdx.x;
    if (i >= N_NODES * 16) return;
    int n = i >> 4, c = (i & 15) * 4;
    float v[4];
    #pragma unroll
    for (int j = 0; j < 4; ++j) {
        int cc = c + j;
        v[j] = (cc < 50) ? x[n * 50 + cc] : 0.0f;
    }
    u16 h[4];
    #pragma unroll
    for (int j = 0; j < 4; ++j) h[j] = f2bf(v[j]);
    *(uint2*)(abuf1 + (size_t)n * 128 + 64 + c) = *(const uint2*)h;
    *(u32*)(gbuf1 + (size_t)n * 64 + c) = pack4fp8(v[0], v[1], v[2], v[3]);
}

// all three weight buffers in one launch
__global__ void conv_w_all_kernel(const float* __restrict__ Wl1, const float* __restrict__ Wr1,
                                  const float* __restrict__ Wl2, const float* __restrict__ Wr2,
                                  const float* __restrict__ Wl3, const float* __restrict__ Wr3,
                                  u16* __restrict__ wb1, u16* __restrict__ wb2,
                                  u16* __restrict__ wb3) {
    int i = blockIdx.x * blockDim.x + threadIdx.x;
    // ranges: wb1 128x64, wb2 256x128, wb3 512x256  (o x c-pad each, dual halves)
    if (i < 128 * 64) {
        int o = i / 64, c = i % 64;
        float vl = (c < 50) ? Wl1[o * 50 + c] : 0.0f;
        float vr = (c < 50) ? Wr1[o * 50 + c] : 0.0f;
        wb1[(size_t)o * 128 + c] = f2bf(vl);
        wb1[(size_t)o * 128 + 64 + c] = f2bf(vr);
        return;
    }
    i -= 128 * 64;
    if (i < 256 * 128) {
        int o = i / 128, c = i % 128;
        wb2[(size_t)o * 256 + c] = f2bf(Wl2[o * 128 + c]);
        wb2[(size_t)o * 256 + 128 + c] = f2bf(Wr2[o * 128 + c]);
        return;
    }
    i -= 256 * 128;
    if (i < 512 * 256) {
        int o = i / 256, c = i % 256;
        wb3[(size_t)o * 512 + c] = f2bf(Wl3[o * 256 + c]);
        wb3[(size_t)o * 512 + 256 + c] = f2bf(Wr3[o * 256 + c]);
    }
}

// ---------------------------------------------------------------------------
// CSR gather mean-aggregation over fp8 rows.
// Row = DINP fp8 = DINP bytes; LPR lanes x 16B per row; EPW = 64/LPR edges
// per wave-iter; fp32 accumulate; cross-sub shfl reduce; bf16 agg out.
// ---------------------------------------------------------------------------
template<int DINP>
__global__ __launch_bounds__(256) void csr_agg_kernel(const int* __restrict__ starts,
                                                      const int* __restrict__ csr,
                                                      const u8* __restrict__ gbuf,
                                                      u16* __restrict__ abuf, int strideA) {
    constexpr int LPR = DINP / 16;   // 4 / 8 / 16
    constexpr int EPW = 64 / LPR;    // 16 / 8 / 4
    const int wave = threadIdx.x >> 6, lane = threadIdx.x & 63;
    const int n = blockIdx.x * 4 + wave;
    if (n >= N_NODES) return;
    const int sub = lane / LPR;
    const int li = lane % LPR;
    const int s0 = starts[n], s1 = starts[n + 1];

    float acc[16] = {};

    int e = s0 + sub;
    for (; e + EPW < s1; e += 2 * EPW) {
        int i0 = csr[e], i1 = csr[e + EPW];
        uint4 u0 = *(const uint4*)(gbuf + (size_t)i0 * DINP + li * 16);
        uint4 u1 = *(const uint4*)(gbuf + (size_t)i1 * DINP + li * 16);
        acc16fp8(acc, u0);
        acc16fp8(acc, u1);
    }
    for (; e < s1; e += EPW) {
        int i0 = csr[e];
        uint4 u0 = *(const uint4*)(gbuf + (size_t)i0 * DINP + li * 16);
        acc16fp8(acc, u0);
    }

    // fold EPW sub-groups down to sub 0
    #pragma unroll
    for (int off = 32; off >= LPR; off >>= 1) {
        #pragma unroll
        for (int c = 0; c < 16; ++c) acc[c] += __shfl_down(acc[c], off);
    }

    if (lane < LPR) {
        float sc = 1.0f / fmaxf((float)(s1 - s0), 1.0f);
        u16 h[16];
        #pragma unroll
        for (int c = 0; c < 16; ++c) h[c] = f2bf(acc[c] * sc);
        u16* o = abuf + (size_t)n * strideA + li * 16;
        *(uint4*)o = *(const uint4*)&h[0];
        *(uint4*)(o + 8) = *(const uint4*)&h[8];
    }
}

// ---------------------------------------------------------------------------
// bf16 MFMA GEMM (R5/R6 core): 3-deep LDS ring, global_load_lds(16B), raw
// s_barrier + manual vmcnt, XCD-chunked swizzle. 128x128 tile, 4 waves 2x2.
// ACT 0: leaky_relu, 1: relu.
// MODE 2: store bf16 at out[..] AND fp8 at g8[node*gDOUT+o]
// MODE 3: store fp8 only at g8[node*gDOUT+o]
// ---------------------------------------------------------------------------
template<int K, int NB, int ACT, int MODE>
__global__ __launch_bounds__(256) void gemm_bf16_kernel(
    const u16* __restrict__ A, const u16* __restrict__ W,
    const float* __restrict__ bias,
    u16* __restrict__ out, int outStride, int outOff,
    u8* __restrict__ g8, int gDOUT, int N)
{
    constexpr int NKB = K / 32;
    constexpr int MT = M_PAD / 128;          // 391 m-tiles
    constexpr int MCHUNK = (MT + 7) / 8;     // 49 per XCD
    __shared__ __align__(16) u16 As[3][128 * 32];
    __shared__ __align__(16) u16 Bs[3][128 * 32];

    const int bx = blockIdx.x;
    const int xcd = bx & 7;
    const int seq = bx >> 3;
    const int n = seq % NB;
    const int m = xcd * MCHUNK + seq / NB;
    if (m >= MT) return;
    const int bm = m * 128;
    const int bn = n * 128;

    const int tid = threadIdx.x;
    const int wave = tid >> 6, lane = tid & 63;
    const int wm = (wave & 1) * 64, wn = (wave >> 1) * 64;
    const int lm = lane & 15, lq = lane >> 4;

    const int srow = wave * 32 + (lane >> 2);
    const int scol = (lane & 3) * 8;
    const u16* gA = A + (size_t)(bm + srow) * K + scol;
    const u16* gB = W + (size_t)(bn + srow) * K + scol;
    const int lbase = wave * 32 * 32;

    auto stage = [&](int s, int r) {
        const int ko = s * 32;
        load_lds16(gA + ko,                  &As[r][lbase]);
        load_lds16(gA + (size_t)16 * K + ko, &As[r][lbase + 16 * 32]);
        load_lds16(gB + ko,                  &Bs[r][lbase]);
        load_lds16(gB + (size_t)16 * K + ko, &Bs[r][lbase + 16 * 32]);
    };

    floatx4 acc[4][4] = {};

    stage(0, 0);
    stage(1, 1);

    #pragma unroll
    for (int kb = 0; kb < NKB; ++kb) {
        if (kb + 2 < NKB) stage(kb + 2, (kb + 2) % 3);
        const int rem = NKB - 1 - kb;
        if (rem >= 2)      waitcnt_vm<8>();
        else if (rem == 1) waitcnt_vm<4>();
        else               waitcnt_vm<0>();
        raw_barrier();

        const int r = kb % 3;
        bf16x8 af[4], bfr[4];
        #pragma unroll
        for (int mi = 0; mi < 4; ++mi)
            af[mi] = *(const bf16x8*)&As[r][(wm + mi * 16 + lm) * 32 + lq * 8];
        #pragma unroll
        for (int ni = 0; ni < 4; ++ni)
            bfr[ni] = *(const bf16x8*)&Bs[r][(wn + ni * 16 + lm) * 32 + lq * 8];
        #pragma unroll
        for (int mi = 0; mi < 4; ++mi)
            #pragma unroll
            for (int ni = 0; ni < 4; ++ni)
                acc[mi][ni] = __builtin_amdgcn_mfma_f32_16x16x32_bf16(
                    af[mi], bfr[ni], acc[mi][ni], 0, 0, 0);
        raw_barrier();
    }

    // epilogue: D row=node (bm+wm+mi*16+lq*4+r), col=o (bn+wn+ni*16+lm)
    #pragma unroll
    for (int mi = 0; mi < 4; ++mi) {
        int node0 = bm + wm + mi * 16 + lq * 4;
        #pragma unroll
        for (int ni = 0; ni < 4; ++ni) {
            int o = bn + wn + ni * 16 + lm;
            float bi = bias[o];
            #pragma unroll
            for (int r = 0; r < 4; ++r) {
                int node = node0 + r;
                if (node >= N) continue;
                float v = acc[mi][ni][r] + bi;
                if (ACT == 0) v = (v > 0.0f) ? v : 0.01f * v;
                else          v = fmaxf(v, 0.0f);
                if (MODE == 2)
                    out[(size_t)node * outStride + outOff + o] = f2bf(v);
                g8[(size_t)node * gDOUT + o] = f2fp8(v);
            }
        }
    }
}

// ---------------------------------------------------------------------------
// global mean pool over fp8 x3 (batch sorted, no atomics). 128 thr x 4 cols.
// ---------------------------------------------------------------------------
__global__ __launch_bounds__(128) void pool_kernel(const u8* __restrict__ x3,
                                                   const int* __restrict__ gstart,
                                                   const float* __restrict__ cntinv,
                                                   float* __restrict__ pool) {
    const int g = blockIdx.x;
    const int c = threadIdx.x * 4;
    const int n0 = gstart[g], n1 = gstart[g + 1];
    float a[4] = {};
    for (int n = n0; n < n1; ++n) {
        u32 w = *(const u32*)(x3 + (size_t)n * 512 + c);
        floatx2 lo = __builtin_amdgcn_cvt_pk_f32_fp8((int)w, false);
        floatx2 hi = __builtin_amdgcn_cvt_pk_f32_fp8((int)w, true);
        a[0] += lo[0]; a[1] += lo[1]; a[2] += hi[0]; a[3] += hi[1];
    }
    const float sc = cntinv[g];
    #pragma unroll
    for (int j = 0; j < 4; ++j) pool[(size_t)g * 512 + c + j] = a[j] * sc;
}

// ---------------------------------------------------------------------------
// small dense layers over 512 graph rows (fp32 head)
// ---------------------------------------------------------------------------
template<int DIN, int DOUT, int ACT>
__global__ void dense_small_kernel(const float* __restrict__ X,
                                   const float* __restrict__ W,
                                   const float* __restrict__ b,
                                   float* __restrict__ Y)
{
    __shared__ float xs[DIN];
    const int g = blockIdx.x;
    for (int k = threadIdx.x; k < DIN; k += blockDim.x)
        xs[k] = X[g * DIN + k];
    __syncthreads();
    for (int o = threadIdx.x; o < DOUT; o += blockDim.x) {
        float s = b[o];
        #pragma unroll 4
        for (int k = 0; k < DIN; ++k) s += xs[k] * W[o * DIN + k];
        if (ACT == 1) s = fmaxf(s, 0.0f);
        if (ACT == 2) s = 1.0f / (1.0f + expf(-s));
        Y[g * DOUT + o] = s;
    }
}

// ---------------------------------------------------------------------------
extern "C" void kernel_launch(void* const* d_in, const int* in_sizes, int n_in,
                              void* d_out, int out_size, void* d_ws, size_t ws_size,
                              hipStream_t stream)
{
    const float* x     = (const float*)d_in[0];
    const int*   ei    = (const int*)  d_in[1];
    const int*   batch = (const int*)  d_in[2];
    const float* Wl1   = (const float*)d_in[3];
    const float* bl1   = (const float*)d_in[4];
    const float* Wr1   = (const float*)d_in[5];
    const float* Wl2   = (const float*)d_in[6];
    const float* bl2   = (const float*)d_in[7];
    const float* Wr2   = (const float*)d_in[8];
    const float* Wl3   = (const float*)d_in[9];
    const float* bl3   = (const float*)d_in[10];
    const float* Wr3   = (const float*)d_in[11];
    const float* Wf1   = (const float*)d_in[12];
    const float* bf1   = (const float*)d_in[13];
    const float* Wf2   = (const float*)d_in[14];
    const float* bf2   = (const float*)d_in[15];
    const float* Wo    = (const float*)d_in[16];
    const float* bo    = (const float*)d_in[17];

    const int* src = ei;
    const int* dst = ei + N_EDGES;

    // ---- workspace layout ----
    char* p = (char*)d_ws;
    auto alloc = [&](size_t bytes) { char* r = p; p += (bytes + 255) & ~(size_t)255; return r; };
    // persistent region
    int*   gstart = (int*)  alloc(513 * 4);
    float* cntinv = (float*)alloc(512 * 4);
    float* pool   = (float*)alloc((size_t)512 * 512 * 4);
    float* x4     = (float*)alloc((size_t)512 * 256 * 4);
    float* x5     = (float*)alloc((size_t)512 * 128 * 4);
    u16*   abuf3  = (u16*)  alloc((size_t)M_PAD * 512 * 2);   // 51.2 MB
    u16*   wb3    = (u16*)  alloc((size_t)512 * 512 * 2);
    u8*    gbuf1  = (u8*)   alloc((size_t)M_PAD * 64);        // 3.2 MB
    u8*    gbuf2  = (u8*)   alloc((size_t)M_PAD * 128);       // 6.4 MB
    u8*    gbuf3  = (u8*)   alloc((size_t)M_PAD * 256);       // 12.8 MB
    // union region: phase A (CSR + early layers) vs phase B (x3 fp8)
    char* ubase = p;
    int*   degi   = (int*)  alloc(50176 * 4);
    int*   cursor = (int*)  alloc(50176 * 4);
    int*   starts = (int*)  alloc(50432 * 4);
    int*   bsum   = (int*)  alloc(256 * 4);
    int*   boff   = (int*)  alloc(256 * 4);
    int*   csr    = (int*)  alloc((size_t)N_EDGES * 4);
    u16*   abuf1  = (u16*)  alloc((size_t)M_PAD * 128 * 2);
    u16*   abuf2  = (u16*)  alloc((size_t)M_PAD * 256 * 2);
    u16*   wb1    = (u16*)  alloc((size_t)128 * 128 * 2);
    u16*   wb2    = (u16*)  alloc((size_t)256 * 256 * 2);
    u8*    x3buf8 = (u8*)ubase;   // 25.6 MB, overlays phase A (dead by gemm3)

    // ---- CSR build ----
    hipMemsetAsync(degi, 0, 2 * 50176 * 4, stream);   // degi + cursor (adjacent)
    count_int_kernel<<<(N_EDGES + 255) / 256, 256, 0, stream>>>(dst, degi, N_EDGES);
    scan1_kernel<<<196, 256, 0, stream>>>(degi, starts, bsum);
    scan2_kernel<<<1, 256, 0, stream>>>(bsum, boff, starts, 196);
    scan3_kernel<<<196, 256, 0, stream>>>(starts, boff);
    fill_csr_kernel<<<(N_EDGES + 255) / 256, 256, 0, stream>>>(src, dst, starts, cursor, csr);
    gstart_kernel<<<196, 256, 0, stream>>>(batch, gstart);
    cntinv_kernel<<<2, 256, 0, stream>>>(gstart, cntinv);

    // ---- conversions ----
    conv_x_kernel<<<(N_NODES * 16 + 255) / 256, 256, 0, stream>>>(x, abuf1, gbuf1);
    conv_w_all_kernel<<<(172032 + 255) / 256, 256, 0, stream>>>(
        Wl1, Wr1, Wl2, Wr2, Wl3, Wr3, wb1, wb2, wb3);

    const int GB = 12500;
    const int GEMM_GRID = 49 * 8;

    // ---- layer 1: 50 -> 128, leaky_relu ----
    csr_agg_kernel<64><<<GB, 256, 0, stream>>>(starts, csr, gbuf1, abuf1, 128);
    gemm_bf16_kernel<128, 1, 0, 2><<<GEMM_GRID * 1, 256, 0, stream>>>(
        abuf1, wb1, bl1, abuf2, 256, 128, gbuf2, 128, N_NODES);

    // ---- layer 2: 128 -> 256, relu ----
    csr_agg_kernel<128><<<GB, 256, 0, stream>>>(starts, csr, gbuf2, abuf2, 256);
    gemm_bf16_kernel<256, 2, 1, 2><<<GEMM_GRID * 2, 256, 0, stream>>>(
        abuf2, wb2, bl2, abuf3, 512, 256, gbuf3, 256, N_NODES);

    // ---- layer 3: 256 -> 512, relu -> x3 fp8, then pool (no atomics) ----
    csr_agg_kernel<256><<<GB, 256, 0, stream>>>(starts, csr, gbuf3, abuf3, 512);
    gemm_bf16_kernel<512, 4, 1, 3><<<GEMM_GRID * 4, 256, 0, stream>>>(
        abuf3, wb3, bl3, nullptr, 0, 0, x3buf8, 512, N_NODES);
    pool_kernel<<<N_GRAPHS, 128, 0, stream>>>(x3buf8, gstart, cntinv, pool);

    // ---- MLP head (fp32) ----
    dense_small_kernel<512, 256, 1><<<N_GRAPHS, 256, 0, stream>>>(pool, Wf1, bf1, x4);
    dense_small_kernel<256, 128, 1><<<N_GRAPHS, 128, 0, stream>>>(x4, Wf2, bf2, x5);
    dense_small_kernel<128, 1, 2><<<N_GRAPHS, 64, 0, stream>>>(x5, Wo, bo, (float*)d_out);
}

// Round 8
// 441.255 us; speedup vs baseline: 1.3890x; 1.0643x over previous
//
#include <hip/hip_runtime.h>
#include <math.h>

#define N_NODES 50000
#define N_EDGES 800000
#define N_GRAPHS 512
#define M_PAD 50048   // N_NODES rounded up to 128

typedef unsigned char u8;
typedef unsigned short u16;
typedef unsigned int u32;
typedef long i64;
using floatx4 = __attribute__((ext_vector_type(4))) float;
using floatx2 = __attribute__((ext_vector_type(2))) float;

__device__ __forceinline__ float bf2f(u16 h) {
    union { u32 u; float f; } v; v.u = ((u32)h) << 16; return v.f;
}
// f32 -> OCP e4m3 (single byte via HW pack)
__device__ __forceinline__ u8 f2fp8(float v) {
    return (u8)(__builtin_amdgcn_cvt_pk_fp8_f32(v, v, 0, false) & 0xFF);
}
__device__ __forceinline__ u32 pack4fp8(float a, float b, float c, float d) {
    u32 p = __builtin_amdgcn_cvt_pk_fp8_f32(a, b, 0, false);
    return __builtin_amdgcn_cvt_pk_fp8_f32(c, d, p, true);
}
// accumulate 16 fp8 (one uint4) into acc[16]
__device__ __forceinline__ void acc16fp8(float* acc, uint4 u) {
    const u32 w[4] = {u.x, u.y, u.z, u.w};
    #pragma unroll
    for (int j = 0; j < 4; ++j) {
        floatx2 lo = __builtin_amdgcn_cvt_pk_f32_fp8((int)w[j], false);
        floatx2 hi = __builtin_amdgcn_cvt_pk_f32_fp8((int)w[j], true);
        acc[j * 4 + 0] += lo[0]; acc[j * 4 + 1] += lo[1];
        acc[j * 4 + 2] += hi[0]; acc[j * 4 + 3] += hi[1];
    }
}

// async global->LDS, 16 B per lane; LDS dest = base + lane*16 (wave-uniform base)
__device__ __forceinline__ void load_lds16(const u8* g, u8* l) {
    __builtin_amdgcn_global_load_lds(
        (const __attribute__((address_space(1))) u32*)g,
        (__attribute__((address_space(3))) u32*)l, 16, 0, 0);
}
template<int N> __device__ __forceinline__ void waitcnt_vm() {
    __builtin_amdgcn_s_waitcnt(0x0F70 | N);
}
__device__ __forceinline__ void raw_barrier() {
    asm volatile("s_barrier" ::: "memory");
}

// ---------------------------------------------------------------------------
// CSR build
// ---------------------------------------------------------------------------
__global__ void count_int_kernel(const int* __restrict__ idx, int* __restrict__ cnt, int n) {
    int i = blockIdx.x * blockDim.x + threadIdx.x;
    if (i < n) atomicAdd(&cnt[idx[i]], 1);
}

__global__ void scan1_kernel(const int* __restrict__ degi, int* __restrict__ starts,
                             int* __restrict__ bsum) {
    __shared__ int s[256];
    int t = threadIdx.x, i = blockIdx.x * 256 + t;
    int v = (i < N_NODES) ? degi[i] : 0;
    s[t] = v; __syncthreads();
    for (int off = 1; off < 256; off <<= 1) {
        int x = (t >= off) ? s[t - off] : 0;
        __syncthreads();
        s[t] += x;
        __syncthreads();
    }
    if (i < N_NODES) starts[i] = s[t] - v;
    if (t == 255) bsum[blockIdx.x] = s[255];
}

__global__ void scan2_kernel(const int* __restrict__ bsum, int* __restrict__ boff,
                             int* __restrict__ starts, int nb) {
    __shared__ int s[256];
    int t = threadIdx.x;
    int v = (t < nb) ? bsum[t] : 0;
    s[t] = v; __syncthreads();
    for (int off = 1; off < 256; off <<= 1) {
        int x = (t >= off) ? s[t - off] : 0;
        __syncthreads();
        s[t] += x;
        __syncthreads();
    }
    if (t < nb) boff[t] = s[t] - v;
    if (t == nb - 1) starts[N_NODES] = s[t];
}

__global__ void scan3_kernel(int* __restrict__ starts, const int* __restrict__ boff) {
    int i = blockIdx.x * 256 + threadIdx.x;
    if (i < N_NODES) starts[i] += boff[blockIdx.x];
}

__global__ void fill_csr_kernel(const int* __restrict__ src, const int* __restrict__ dst,
                                const int* __restrict__ starts, int* __restrict__ cursor,
                                int* __restrict__ csr) {
    int e = blockIdx.x * blockDim.x + threadIdx.x;
    if (e >= N_EDGES) return;
    int d = dst[e];
    int p = atomicAdd(&cursor[d], 1);
    csr[starts[d] + p] = src[e];
}

__global__ void gstart_kernel(const int* __restrict__ batch, int* __restrict__ gstart) {
    int i = blockIdx.x * blockDim.x + threadIdx.x;
    if (i >= N_NODES) return;
    int b = batch[i];
    int bp = (i == 0) ? -1 : batch[i - 1];
    for (int g = bp + 1; g <= b; ++g) gstart[g] = i;
    if (i == N_NODES - 1)
        for (int g = b + 1; g <= N_GRAPHS; ++g) gstart[g] = N_NODES;
}

__global__ void cntinv_kernel(const int* __restrict__ gstart, float* __restrict__ cntinv) {
    int g = blockIdx.x * blockDim.x + threadIdx.x;
    if (g < N_GRAPHS) cntinv[g] = 1.0f / fmaxf((float)(gstart[g + 1] - gstart[g]), 1.0f);
}

// ---------------------------------------------------------------------------
// conversions
// ---------------------------------------------------------------------------
// x -> fp8 self half of abuf1 (cols 64..127, zero-padded past 50)
__global__ void conv_x_kernel(const float* __restrict__ x, u8* __restrict__ abuf1) {
    int i = blockIdx.x * blockDim.x + threadIdx.x;
    if (i >= N_NODES * 16) return;
    int n = i >> 4, c = (i & 15) * 4;
    float v[4];
    #pragma unroll
    for (int j = 0; j < 4; ++j) {
        int cc = c + j;
        v[j] = (cc < 50) ? x[n * 50 + cc] : 0.0f;
    }
    *(u32*)(abuf1 + (size_t)n * 128 + 64 + c) = pack4fp8(v[0], v[1], v[2], v[3]);
}

// all three weight buffers (fp8, [Wl | Wr] per row) in one launch
__global__ void conv_w_all_kernel(const float* __restrict__ Wl1, const float* __restrict__ Wr1,
                                  const float* __restrict__ Wl2, const float* __restrict__ Wr2,
                                  const float* __restrict__ Wl3, const float* __restrict__ Wr3,
                                  u8* __restrict__ wb1, u8* __restrict__ wb2,
                                  u8* __restrict__ wb3) {
    int i = blockIdx.x * blockDim.x + threadIdx.x;
    if (i < 128 * 64) {
        int o = i / 64, c = i % 64;
        float vl = (c < 50) ? Wl1[o * 50 + c] : 0.0f;
        float vr = (c < 50) ? Wr1[o * 50 + c] : 0.0f;
        wb1[(size_t)o * 128 + c] = f2fp8(vl);
        wb1[(size_t)o * 128 + 64 + c] = f2fp8(vr);
        return;
    }
    i -= 128 * 64;
    if (i < 256 * 128) {
        int o = i / 128, c = i % 128;
        wb2[(size_t)o * 256 + c] = f2fp8(Wl2[o * 128 + c]);
        wb2[(size_t)o * 256 + 128 + c] = f2fp8(Wr2[o * 128 + c]);
        return;
    }
    i -= 256 * 128;
    if (i < 512 * 256) {
        int o = i / 256, c = i % 256;
        wb3[(size_t)o * 512 + c] = f2fp8(Wl3[o * 256 + c]);
        wb3[(size_t)o * 512 + 256 + c] = f2fp8(Wr3[o * 256 + c]);
    }
}

// ---------------------------------------------------------------------------
// CSR gather mean-aggregation, in-place on the fp8 layer buffer:
// row = [agg (DINP fp8) | self (DINP fp8)]; gathers self[src], writes agg[n].
// LPR lanes x 16B per row; EPW = 64/LPR edges per wave-iter; fp32 accum.
// ---------------------------------------------------------------------------
template<int DINP>
__global__ __launch_bounds__(256) void csr_agg_kernel(const int* __restrict__ starts,
                                                      const int* __restrict__ csr,
                                                      u8* __restrict__ abuf) {
    constexpr int STRIDE = 2 * DINP;
    constexpr int LPR = DINP / 16;   // 4 / 8 / 16
    constexpr int EPW = 64 / LPR;    // 16 / 8 / 4
    const int wave = threadIdx.x >> 6, lane = threadIdx.x & 63;
    const int n = blockIdx.x * 4 + wave;
    if (n >= N_NODES) return;
    const int sub = lane / LPR;
    const int li = lane % LPR;
    const int s0 = starts[n], s1 = starts[n + 1];

    float acc[16] = {};
    const u8* xin = abuf + DINP;     // self half

    int e = s0 + sub;
    for (; e + EPW < s1; e += 2 * EPW) {
        int i0 = csr[e], i1 = csr[e + EPW];
        uint4 u0 = *(const uint4*)(xin + (size_t)i0 * STRIDE + li * 16);
        uint4 u1 = *(const uint4*)(xin + (size_t)i1 * STRIDE + li * 16);
        acc16fp8(acc, u0);
        acc16fp8(acc, u1);
    }
    for (; e < s1; e += EPW) {
        int i0 = csr[e];
        uint4 u0 = *(const uint4*)(xin + (size_t)i0 * STRIDE + li * 16);
        acc16fp8(acc, u0);
    }

    #pragma unroll
    for (int off = 32; off >= LPR; off >>= 1) {
        #pragma unroll
        for (int c = 0; c < 16; ++c) acc[c] += __shfl_down(acc[c], off);
    }

    if (lane < LPR) {
        float sc = 1.0f / fmaxf((float)(s1 - s0), 1.0f);
        uint4 o;
        o.x = pack4fp8(acc[0] * sc, acc[1] * sc, acc[2] * sc, acc[3] * sc);
        o.y = pack4fp8(acc[4] * sc, acc[5] * sc, acc[6] * sc, acc[7] * sc);
        o.z = pack4fp8(acc[8] * sc, acc[9] * sc, acc[10] * sc, acc[11] * sc);
        o.w = pack4fp8(acc[12] * sc, acc[13] * sc, acc[14] * sc, acc[15] * sc);
        *(uint4*)(abuf + (size_t)n * STRIDE + li * 16) = o;
    }
}

// ---------------------------------------------------------------------------
// fp8 MFMA GEMM: 3-deep LDS ring, global_load_lds(16B), raw s_barrier +
// manual vmcnt (prefetches stay in flight across barriers), XCD-chunked
// swizzle. 128x128 tile, 4 waves 2x2, 4x4 mfma_f32_16x16x32_fp8_fp8.
// A rows = K fp8 bytes. Frag reads are ds_read_b64 (half the LDS traffic
// of the bf16 version - the measured bottleneck).
// Epilogue: act, then store fp8 at out8[node*gstride + goff + o].
// ACT 0: leaky_relu, 1: relu.
// ---------------------------------------------------------------------------
template<int K, int NB, int ACT>
__global__ __launch_bounds__(256) void gemm_fp8_kernel(
    const u8* __restrict__ A, const u8* __restrict__ W,
    const float* __restrict__ bias,
    u8* __restrict__ out8, int gstride, int goff, int N)
{
    constexpr int NKB = K / 32;
    constexpr int MT = M_PAD / 128;          // 391 m-tiles
    constexpr int MCHUNK = (MT + 7) / 8;     // 49 per XCD
    __shared__ __align__(16) u8 As[3][128 * 32];
    __shared__ __align__(16) u8 Bs[3][128 * 32];

    const int bx = blockIdx.x;
    const int xcd = bx & 7;
    const int seq = bx >> 3;
    const int n = seq % NB;
    const int m = xcd * MCHUNK + seq / NB;
    if (m >= MT) return;
    const int bm = m * 128;
    const int bn = n * 128;

    const int tid = threadIdx.x;
    const int wave = tid >> 6, lane = tid & 63;
    const int wm = (wave & 1) * 64, wn = (wave >> 1) * 64;
    const int lm = lane & 15, lq = lane >> 4;

    // staging: wave w covers rows w*32..w*32+31 (32 B each = 1 load/matrix)
    const int srow = wave * 32 + (lane >> 1);
    const int scol = (lane & 1) * 16;
    const u8* gA = A + (size_t)(bm + srow) * K + scol;
    const u8* gB = W + (size_t)(bn + srow) * K + scol;
    const int lbase = wave * 32 * 32;

    auto stage = [&](int s, int r) {
        const int ko = s * 32;
        load_lds16(gA + ko, &As[r][lbase]);
        load_lds16(gB + ko, &Bs[r][lbase]);
    };

    floatx4 acc[4][4] = {};

    stage(0, 0);
    stage(1, 1);

    #pragma unroll
    for (int kb = 0; kb < NKB; ++kb) {
        if (kb + 2 < NKB) stage(kb + 2, (kb + 2) % 3);
        const int rem = NKB - 1 - kb;
        if (rem >= 2)      waitcnt_vm<4>();
        else if (rem == 1) waitcnt_vm<2>();
        else               waitcnt_vm<0>();
        raw_barrier();

        const int r = kb % 3;
        i64 af[4], bfr[4];
        #pragma unroll
        for (int mi = 0; mi < 4; ++mi)
            af[mi] = *(const i64*)&As[r][(wm + mi * 16 + lm) * 32 + lq * 8];
        #pragma unroll
        for (int ni = 0; ni < 4; ++ni)
            bfr[ni] = *(const i64*)&Bs[r][(wn + ni * 16 + lm) * 32 + lq * 8];
        #pragma unroll
        for (int mi = 0; mi < 4; ++mi)
            #pragma unroll
            for (int ni = 0; ni < 4; ++ni)
                acc[mi][ni] = __builtin_amdgcn_mfma_f32_16x16x32_fp8_fp8(
                    af[mi], bfr[ni], acc[mi][ni], 0, 0, 0);
        raw_barrier();
    }

    // epilogue: D row=node (bm+wm+mi*16+lq*4+r), col=o (bn+wn+ni*16+lm)
    #pragma unroll
    for (int mi = 0; mi < 4; ++mi) {
        int node0 = bm + wm + mi * 16 + lq * 4;
        #pragma unroll
        for (int ni = 0; ni < 4; ++ni) {
            int o = bn + wn + ni * 16 + lm;
            float bi = bias[o];
            #pragma unroll
            for (int r = 0; r < 4; ++r) {
                int node = node0 + r;
                if (node >= N) continue;
                float v = acc[mi][ni][r] + bi;
                if (ACT == 0) v = (v > 0.0f) ? v : 0.01f * v;
                else          v = fmaxf(v, 0.0f);
                out8[(size_t)node * gstride + goff + o] = f2fp8(v);
            }
        }
    }
}

// ---------------------------------------------------------------------------
// global mean pool over fp8 x3 (batch sorted, no atomics). 128 thr x 4 cols.
// ---------------------------------------------------------------------------
__global__ __launch_bounds__(128) void pool_kernel(const u8* __restrict__ x3,
                                                   const int* __restrict__ gstart,
                                                   const float* __restrict__ cntinv,
                                                   float* __restrict__ pool) {
    const int g = blockIdx.x;
    const int c = threadIdx.x * 4;
    const int n0 = gstart[g], n1 = gstart[g + 1];
    float a[4] = {};
    for (int n = n0; n < n1; ++n) {
        u32 w = *(const u32*)(x3 + (size_t)n * 512 + c);
        floatx2 lo = __builtin_amdgcn_cvt_pk_f32_fp8((int)w, false);
        floatx2 hi = __builtin_amdgcn_cvt_pk_f32_fp8((int)w, true);
        a[0] += lo[0]; a[1] += lo[1]; a[2] += hi[0]; a[3] += hi[1];
    }
    const float sc = cntinv[g];
    #pragma unroll
    for (int j = 0; j < 4; ++j) pool[(size_t)g * 512 + c + j] = a[j] * sc;
}

// ---------------------------------------------------------------------------
// small dense layers over 512 graph rows (fp32 head)
// ---------------------------------------------------------------------------
template<int DIN, int DOUT, int ACT>
__global__ void dense_small_kernel(const float* __restrict__ X,
                                   const float* __restrict__ W,
                                   const float* __restrict__ b,
                                   float* __restrict__ Y)
{
    __shared__ float xs[DIN];
    const int g = blockIdx.x;
    for (int k = threadIdx.x; k < DIN; k += blockDim.x)
        xs[k] = X[g * DIN + k];
    __syncthreads();
    for (int o = threadIdx.x; o < DOUT; o += blockDim.x) {
        float s = b[o];
        #pragma unroll 4
        for (int k = 0; k < DIN; ++k) s += xs[k] * W[o * DIN + k];
        if (ACT == 1) s = fmaxf(s, 0.0f);
        if (ACT == 2) s = 1.0f / (1.0f + expf(-s));
        Y[g * DOUT + o] = s;
    }
}

// ---------------------------------------------------------------------------
extern "C" void kernel_launch(void* const* d_in, const int* in_sizes, int n_in,
                              void* d_out, int out_size, void* d_ws, size_t ws_size,
                              hipStream_t stream)
{
    const float* x     = (const float*)d_in[0];
    const int*   ei    = (const int*)  d_in[1];
    const int*   batch = (const int*)  d_in[2];
    const float* Wl1   = (const float*)d_in[3];
    const float* bl1   = (const float*)d_in[4];
    const float* Wr1   = (const float*)d_in[5];
    const float* Wl2   = (const float*)d_in[6];
    const float* bl2   = (const float*)d_in[7];
    const float* Wr2   = (const float*)d_in[8];
    const float* Wl3   = (const float*)d_in[9];
    const float* bl3   = (const float*)d_in[10];
    const float* Wr3   = (const float*)d_in[11];
    const float* Wf1   = (const float*)d_in[12];
    const float* bf1   = (const float*)d_in[13];
    const float* Wf2   = (const float*)d_in[14];
    const float* bf2   = (const float*)d_in[15];
    const float* Wo    = (const float*)d_in[16];
    const float* bo    = (const float*)d_in[17];

    const int* src = ei;
    const int* dst = ei + N_EDGES;

    // ---- workspace layout ----
    char* p = (char*)d_ws;
    auto alloc = [&](size_t bytes) { char* r = p; p += (bytes + 255) & ~(size_t)255; return r; };
    // persistent region
    int*   gstart = (int*)  alloc(513 * 4);
    float* cntinv = (float*)alloc(512 * 4);
    float* pool   = (float*)alloc((size_t)512 * 512 * 4);
    float* x4     = (float*)alloc((size_t)512 * 256 * 4);
    float* x5     = (float*)alloc((size_t)512 * 128 * 4);
    u8*    abuf3  = (u8*)   alloc((size_t)M_PAD * 512);   // 25.6 MB, [agg|self] fp8
    u8*    wb3    = (u8*)   alloc((size_t)512 * 512);
    // union region: phase A (CSR + early layers) vs phase B (x3 fp8)
    char* ubase = p;
    int*   degi   = (int*)  alloc(50176 * 4);
    int*   cursor = (int*)  alloc(50176 * 4);
    int*   starts = (int*)  alloc(50432 * 4);
    int*   bsum   = (int*)  alloc(256 * 4);
    int*   boff   = (int*)  alloc(256 * 4);
    int*   csr    = (int*)  alloc((size_t)N_EDGES * 4);
    u8*    abuf1  = (u8*)   alloc((size_t)M_PAD * 128);   // 6.4 MB
    u8*    abuf2  = (u8*)   alloc((size_t)M_PAD * 256);   // 12.8 MB
    u8*    wb1    = (u8*)   alloc((size_t)128 * 128);
    u8*    wb2    = (u8*)   alloc((size_t)256 * 256);
    u8*    x3buf8 = (u8*)ubase;   // 25.6 MB, overlays phase A (dead by gemm3)

    // ---- CSR build ----
    hipMemsetAsync(degi, 0, 2 * 50176 * 4, stream);   // degi + cursor (adjacent)
    count_int_kernel<<<(N_EDGES + 255) / 256, 256, 0, stream>>>(dst, degi, N_EDGES);
    scan1_kernel<<<196, 256, 0, stream>>>(degi, starts, bsum);
    scan2_kernel<<<1, 256, 0, stream>>>(bsum, boff, starts, 196);
    scan3_kernel<<<196, 256, 0, stream>>>(starts, boff);
    fill_csr_kernel<<<(N_EDGES + 255) / 256, 256, 0, stream>>>(src, dst, starts, cursor, csr);
    gstart_kernel<<<196, 256, 0, stream>>>(batch, gstart);
    cntinv_kernel<<<2, 256, 0, stream>>>(gstart, cntinv);

    // ---- conversions ----
    conv_x_kernel<<<(N_NODES * 16 + 255) / 256, 256, 0, stream>>>(x, abuf1);
    conv_w_all_kernel<<<(172032 + 255) / 256, 256, 0, stream>>>(
        Wl1, Wr1, Wl2, Wr2, Wl3, Wr3, wb1, wb2, wb3);

    const int GB = 12500;
    const int GEMM_GRID = 49 * 8;

    // ---- layer 1: 50 -> 128, leaky_relu ----
    csr_agg_kernel<64><<<GB, 256, 0, stream>>>(starts, csr, abuf1);
    gemm_fp8_kernel<128, 1, 0><<<GEMM_GRID * 1, 256, 0, stream>>>(
        abuf1, wb1, bl1, abuf2, 256, 128, N_NODES);

    // ---- layer 2: 128 -> 256, relu ----
    csr_agg_kernel<128><<<GB, 256, 0, stream>>>(starts, csr, abuf2);
    gemm_fp8_kernel<256, 2, 1><<<GEMM_GRID * 2, 256, 0, stream>>>(
        abuf2, wb2, bl2, abuf3, 512, 256, N_NODES);

    // ---- layer 3: 256 -> 512, relu -> x3 fp8, then pool (no atomics) ----
    csr_agg_kernel<256><<<GB, 256, 0, stream>>>(starts, csr, abuf3);
    gemm_fp8_kernel<512, 4, 1><<<GEMM_GRID * 4, 256, 0, stream>>>(
        abuf3, wb3, bl3, x3buf8, 512, 0, N_NODES);
    pool_kernel<<<N_GRAPHS, 128, 0, stream>>>(x3buf8, gstart, cntinv, pool);

    // ---- MLP head (fp32) ----
    dense_small_kernel<512, 256, 1><<<N_GRAPHS, 256, 0, stream>>>(pool, Wf1, bf1, x4);
    dense_small_kernel<256, 128, 1><<<N_GRAPHS, 128, 0, stream>>>(x4, Wf2, bf2, x5);
    dense_small_kernel<128, 1, 2><<<N_GRAPHS, 64, 0, stream>>>(x5, Wo, bo, (float*)d_out);
}